// Round 10
// baseline (511.010 us; speedup 1.0000x reference)
//
#include <hip/hip_runtime.h>

#define D 128
#define ND 100000
#define NP 50000
#define NE_DD 800000
#define NE_DP 600000
#define NE_PD 600000
#define NE_TOT 2000000

#define NTOT 250000      /* concatenated dst space: [dd:100k][pd:100k][dp:50k] */
#define NBC 490          /* coarse buckets, 512 nodes each (490*512 = 250880) */
#define NC 250880
#define CHUNKA 4096      /* edges per binning block */
#define NBLKA 489        /* ceil(2M/4096) */
#define CHUNKIT 16       /* CHUNKA/256 */
#define SEGCAP 8192      /* max edges per coarse bucket (expected max ~6.6k) */

/* transform: drug waves 32 rows (2 outputs), prot waves 64 rows */
#define TF_BD 782        /* ceil(100000/128) */
#define TF_BP 196        /* ceil(50000/256)  */
/* fused gather+node_update: 128-row blocks, wave = 32 rows (M_rep=2) */
#define NU_BD 782        /* ceil(100000/128) */
#define NU_BP 391        /* ceil(50000/128)  */

#define AGG_STRIDE 272   /* LDS agg row stride bytes: 256 + 16 pad */

typedef __bf16 bf16;
typedef __attribute__((ext_vector_type(8))) __bf16 bf16x8;
typedef __attribute__((ext_vector_type(2))) __bf16 bf16x2;
typedef __attribute__((ext_vector_type(4))) float f32x4;
typedef __attribute__((ext_vector_type(2))) float f32x2;

// ---------------- workspace layout (byte offsets, 16B-aligned) -------------
#define OFF_WDD   0UL
#define OFF_WDP   32768UL
#define OFF_WPD   65536UL
#define OFF_WDRUG 98304UL
#define OFF_WPROT 163840UL
#define OFF_YDD   229376UL                      /* 100k x 128 fp8 */
#define OFF_YDP   (OFF_YDD + 25600000UL)        /* 100k x 128 fp8 */
#define OFF_YPD   (OFF_YDP + 25600000UL)        /* 50k x 128 fp8 */
#define OFF_BCNT  (OFF_YPD + 12800000UL)        /* NBC ints (memset to 0) */
#define OFF_GCUR  (OFF_BCNT + 2048UL)           /* NBC ints */
#define OFF_CBASE (OFF_GCUR + 2048UL)           /* NBC+1 ints */
#define OFF_RP    (OFF_CBASE + 2048UL)          /* NC ints (row ptrs) */
#define OFF_PAIRS (OFF_RP + 1003520UL)          /* 2M u32 packed (ldst<<17|src) */
#define OFF_POOL  (OFF_PAIRS + 16000000UL)      /* 2M ints (node-grouped src) */

// ---------------- fp8 e4m3 encode (values >= 0 only; relu outputs) ---------
__device__ __forceinline__ unsigned enc1(float f)
{
    unsigned t = __float_as_uint(f * 0x1p-120f);
    t = (t + 0x80000u) >> 20;
    return t > 0x7Eu ? 0x7Eu : t;
}
__device__ __forceinline__ unsigned enc4(float a, float b, float c, float d)
{
    return enc1(a) | (enc1(b) << 8) | (enc1(c) << 16) | (enc1(d) << 24);
}

// ---------------- prep: weights->bf16  +  coarse histogram -----------------
__global__ __launch_bounds__(256) void prep_kernel(
    const float* __restrict__ w0, const float* __restrict__ w1,
    const float* __restrict__ w2, const float* __restrict__ w3,
    const float* __restrict__ w4,
    bf16* __restrict__ o0, bf16* __restrict__ o1, bf16* __restrict__ o2,
    bf16* __restrict__ o3, bf16* __restrict__ o4,
    const int* __restrict__ dd_dst, const int* __restrict__ pd_dst,
    const int* __restrict__ dp_dst, int* __restrict__ bcnt)
{
    int m = blockIdx.y;
    int t = threadIdx.x;
    if (m == 5) {
        __shared__ int h[NBC];
        for (int i = t; i < NBC; i += 256) h[i] = 0;
        __syncthreads();
        for (int e = blockIdx.x * 256 + t; e < NE_TOT; e += 128 * 256) {
            int didx;
            if (e < NE_DD) didx = dd_dst[e];
            else if (e < NE_DD + NE_PD) didx = ND + pd_dst[e - NE_DD];
            else didx = 2 * ND + dp_dst[e - NE_DD - NE_PD];
            atomicAdd(&h[didx >> 9], 1);
        }
        __syncthreads();
        for (int i = t; i < NBC; i += 256)
            if (h[i]) atomicAdd(&bcnt[i], h[i]);
        return;
    }
    int i = blockIdx.x * 256 + t;
    const float* src; bf16* dst; int n; bool perm;
    switch (m) {
        case 0: src = w0; dst = o0; n = D * D; perm = false; break;
        case 1: src = w1; dst = o1; n = D * D; perm = false; break;
        case 2: src = w2; dst = o2; n = D * D; perm = false; break;
        case 3: src = w3; dst = o3; n = D * 2 * D; perm = true; break;
        default: src = w4; dst = o4; n = D * 2 * D; perm = true; break;
    }
    if (i < n) {
        int si = i;
        if (perm) {
            int col = i & 255;
            if (col >= 128) {
                int p = col - 128;
                si = (i & ~255) | (128 + (p & 7) * 16 + (p >> 3));
            }
        }
        dst[i] = (bf16)src[si];
    }
}

// ---------------- exclusive scan over 490 bucket counts (1 block) ----------
__global__ __launch_bounds__(256) void scan_kernel(
    const int* __restrict__ bcnt, int* __restrict__ cbase, int* __restrict__ gcur)
{
    __shared__ int ps[256];
    int t = threadIdx.x;
    int i0 = 2 * t, i1 = 2 * t + 1;
    int c0 = (i0 < NBC) ? bcnt[i0] : 0;
    int c1 = (i1 < NBC) ? bcnt[i1] : 0;
    ps[t] = c0 + c1;
    __syncthreads();
#pragma unroll
    for (int off = 1; off < 256; off <<= 1) {
        int add = (t >= off) ? ps[t - off] : 0;
        __syncthreads();
        ps[t] += add;
        __syncthreads();
    }
    int excl = ps[t] - (c0 + c1);
    if (i0 <= NBC) cbase[i0] = excl;            /* i0==NBC writes the sentinel */
    if (i0 < NBC) gcur[i0] = excl;
    if (i1 < NBC) { cbase[i1] = excl + c0; gcur[i1] = excl + c0; }
}

// ---------------- transforms: y = relu(x @ W^T), permuted cols, fp8 out ----
__device__ __forceinline__ bf16x8 load_a_f32(const float* __restrict__ xr)
{
    float4 f0 = *(const float4*)xr;
    float4 f1 = *(const float4*)(xr + 4);
    bf16x8 a;
    a[0] = (bf16)f0.x; a[1] = (bf16)f0.y; a[2] = (bf16)f0.z; a[3] = (bf16)f0.w;
    a[4] = (bf16)f1.x; a[5] = (bf16)f1.y; a[6] = (bf16)f1.z; a[7] = (bf16)f1.w;
    return a;
}

__device__ __forceinline__ void transform_drug(
    const float* __restrict__ x, const bf16* __restrict__ W1,
    const bf16* __restrict__ W2, unsigned char* __restrict__ y1,
    unsigned char* __restrict__ y2, int blk)
{
    int lane = threadIdx.x & 63;
    int wave = threadIdx.x >> 6;
    int q = lane >> 4, c = lane & 15;
    int mb = blk * 128 + wave * 32;         /* 2 M-tiles per wave, 2 outputs */

    f32x4 acc1[2][8], acc2[2][8];
#pragma unroll
    for (int mt = 0; mt < 2; mt++)
#pragma unroll
        for (int nt = 0; nt < 8; nt++) { acc1[mt][nt] = 0; acc2[mt][nt] = 0; }

#pragma unroll
    for (int kb = 0; kb < 4; kb++) {
        int k = kb * 32 + q * 8;
        bf16x8 a[2];
#pragma unroll
        for (int mt = 0; mt < 2; mt++) {
            int row = min(mb + mt * 16 + c, ND - 1);
            a[mt] = load_a_f32(x + (long)row * D + k);
        }
#pragma unroll
        for (int nt = 0; nt < 8; nt++) {
            bf16x8 b1 = *(const bf16x8*)(W1 + (nt * 16 + c) * D + k);
            bf16x8 b2 = *(const bf16x8*)(W2 + (nt * 16 + c) * D + k);
#pragma unroll
            for (int mt = 0; mt < 2; mt++) {
                acc1[mt][nt] = __builtin_amdgcn_mfma_f32_16x16x32_bf16(a[mt], b1, acc1[mt][nt], 0, 0, 0);
                acc2[mt][nt] = __builtin_amdgcn_mfma_f32_16x16x32_bf16(a[mt], b2, acc2[mt][nt], 0, 0, 0);
            }
        }
    }
#pragma unroll
    for (int mt = 0; mt < 2; mt++)
#pragma unroll
        for (int r = 0; r < 4; r++) {
            int row = mb + mt * 16 + q * 4 + r;
            if (row < ND) {
                float v1[8], v2[8];
#pragma unroll
                for (int nt = 0; nt < 8; nt++) {
                    v1[nt] = fmaxf(acc1[mt][nt][r], 0.f);
                    v2[nt] = fmaxf(acc2[mt][nt][r], 0.f);
                }
                uint2 p1, p2;
                p1.x = enc4(v1[0], v1[1], v1[2], v1[3]);
                p1.y = enc4(v1[4], v1[5], v1[6], v1[7]);
                p2.x = enc4(v2[0], v2[1], v2[2], v2[3]);
                p2.y = enc4(v2[4], v2[5], v2[6], v2[7]);
                *(uint2*)(y1 + (long)row * D + c * 8) = p1;
                *(uint2*)(y2 + (long)row * D + c * 8) = p2;
            }
        }
}

__device__ __forceinline__ void transform_prot(
    const float* __restrict__ x, const bf16* __restrict__ W1,
    unsigned char* __restrict__ y1, int blk)
{
    int lane = threadIdx.x & 63;
    int wave = threadIdx.x >> 6;
    int q = lane >> 4, c = lane & 15;
    int mb = blk * 256 + wave * 64;         /* 4 M-tiles per wave, 1 output */

    f32x4 acc[4][8];
#pragma unroll
    for (int mt = 0; mt < 4; mt++)
#pragma unroll
        for (int nt = 0; nt < 8; nt++) acc[mt][nt] = 0;

#pragma unroll
    for (int kb = 0; kb < 4; kb++) {
        int k = kb * 32 + q * 8;
        bf16x8 a[4];
#pragma unroll
        for (int mt = 0; mt < 4; mt++) {
            int row = min(mb + mt * 16 + c, NP - 1);
            a[mt] = load_a_f32(x + (long)row * D + k);
        }
#pragma unroll
        for (int nt = 0; nt < 8; nt++) {
            bf16x8 b1 = *(const bf16x8*)(W1 + (nt * 16 + c) * D + k);
#pragma unroll
            for (int mt = 0; mt < 4; mt++)
                acc[mt][nt] = __builtin_amdgcn_mfma_f32_16x16x32_bf16(a[mt], b1, acc[mt][nt], 0, 0, 0);
        }
    }
#pragma unroll
    for (int mt = 0; mt < 4; mt++)
#pragma unroll
        for (int r = 0; r < 4; r++) {
            int row = mb + mt * 16 + q * 4 + r;
            if (row < NP) {
                float v[8];
#pragma unroll
                for (int nt = 0; nt < 8; nt++)
                    v[nt] = fmaxf(acc[mt][nt][r], 0.f);
                uint2 p1;
                p1.x = enc4(v[0], v[1], v[2], v[3]);
                p1.y = enc4(v[4], v[5], v[6], v[7]);
                *(uint2*)(y1 + (long)row * D + c * 8) = p1;
            }
        }
}

__global__ __launch_bounds__(256, 2) void transform_kernel(
    const float* __restrict__ x_drug, const float* __restrict__ x_prot,
    const bf16* __restrict__ Wdd, const bf16* __restrict__ Wdp,
    const bf16* __restrict__ Wpd,
    unsigned char* __restrict__ y_dd, unsigned char* __restrict__ y_dp,
    unsigned char* __restrict__ y_pd)
{
    int blk = blockIdx.x;
    if (blk < TF_BD)
        transform_drug(x_drug, Wdd, Wdp, y_dd, y_dp, blk);
    else
        transform_prot(x_prot, Wpd, y_pd, blk - TF_BD);
}

// ---------------- pass A: coarse binning, packed u32 output ----------------
__global__ __launch_bounds__(256) void binA_kernel(
    const int* __restrict__ dd_src, const int* __restrict__ dd_dst,
    const int* __restrict__ pd_src, const int* __restrict__ pd_dst,
    const int* __restrict__ dp_src, const int* __restrict__ dp_dst,
    int* __restrict__ gcur, unsigned* __restrict__ pairs)
{
    __shared__ int h[NBC];
    __shared__ int gb[NBC];
    __shared__ int2 pr[CHUNKA];
    __shared__ unsigned short rk[CHUNKA];
    for (int i = threadIdx.x; i < NBC; i += 256) h[i] = 0;
    __syncthreads();
    int base = blockIdx.x * CHUNKA;
    for (int it = 0; it < CHUNKIT; it++) {
        int idx = it * 256 + threadIdx.x;
        int e = base + idx;
        int didx = -1, sv = 0;
        if (e < NE_TOT) {
            if (e < NE_DD) { didx = dd_dst[e]; sv = dd_src[e]; }
            else if (e < NE_DD + NE_PD) { int u = e - NE_DD; didx = ND + pd_dst[u]; sv = pd_src[u]; }
            else { int u = e - NE_DD - NE_PD; didx = 2 * ND + dp_dst[u]; sv = dp_src[u]; }
            rk[idx] = (unsigned short)atomicAdd(&h[didx >> 9], 1);
        }
        pr[idx] = make_int2(didx, sv);
    }
    __syncthreads();
    for (int b = threadIdx.x; b < NBC; b += 256) {
        int c = h[b];
        gb[b] = c ? atomicAdd(&gcur[b], c) : 0;
    }
    __syncthreads();
    for (int it = 0; it < CHUNKIT; it++) {
        int idx = it * 256 + threadIdx.x;
        int2 p = pr[idx];
        if (p.x >= 0)
            pairs[gb[p.x >> 9] + rk[idx]] =
                ((unsigned)(p.x & 511) << 17) | (unsigned)p.y;
    }
}

// ---------------- pass B: per-bucket LDS counting sort -> pool + rp --------
__global__ __launch_bounds__(256) void sortB_kernel(
    const int* __restrict__ cbase, const unsigned* __restrict__ pairs,
    int* __restrict__ pool, int* __restrict__ rp)
{
    __shared__ int h[512];
    __shared__ int excl[512];
    __shared__ int ps[256];
    __shared__ unsigned short rk[SEGCAP];
    __shared__ int outl[SEGCAP];

    int b = blockIdx.x;
    int s0 = cbase[b], s1 = cbase[b + 1];
    int n = s1 - s0;
    if (n > SEGCAP) n = SEGCAP;   /* safety clamp; expected max ~6.6k */
    int t = threadIdx.x;
    h[t] = 0; h[t + 256] = 0;
    __syncthreads();

    for (int i = t; i < n; i += 256) {
        unsigned p = pairs[s0 + i];
        rk[i] = (unsigned short)atomicAdd(&h[p >> 17], 1);
    }
    __syncthreads();

    int c0 = h[2 * t], c1 = h[2 * t + 1];
    ps[t] = c0 + c1;
    __syncthreads();
#pragma unroll
    for (int off = 1; off < 256; off <<= 1) {
        int add = (t >= off) ? ps[t - off] : 0;
        __syncthreads();
        ps[t] += add;
        __syncthreads();
    }
    int pe = ps[t] - (c0 + c1);
    excl[2 * t] = pe;
    excl[2 * t + 1] = pe + c0;
    __syncthreads();

    int nb = b * 512;
    rp[nb + 2 * t] = s0 + excl[2 * t];
    rp[nb + 2 * t + 1] = s0 + excl[2 * t + 1];

    for (int i = t; i < n; i += 256) {
        unsigned p = pairs[s0 + i];
        outl[excl[p >> 17] + rk[i]] = (int)(p & 0x1FFFFu);
    }
    __syncthreads();
    for (int i = t; i < n; i += 256)
        pool[s0 + i] = outl[i];
}

// ---------------- fused gather + node update -------------------------------
// Phase A: each wave gathers 32 nodes into its 32-row LDS region (bf16,
// identical rounding to the old global agg round-trip).  Phase B: M_rep=2
// GEMM(K=256) + LN epilogue with agg A-fragments from LDS.  Defensive form:
// no early break before the barrier (plain guard), explicit launch_bounds.
__device__ __forceinline__ void accw(unsigned short w, f32x2* acc)
{
    float lo = __uint_as_float((unsigned)(w & 0xFFu) << 20);
    float hi = __uint_as_float((unsigned)(w >> 8) << 20);
    acc->x = fmaf(lo, 0x1p120f, acc->x);
    acc->y = fmaf(hi, 0x1p120f, acc->y);
}

__device__ __forceinline__ void acc_seg(
    const int* __restrict__ pool, int s, int e,
    const unsigned short* __restrict__ y, int lane, f32x2* acc)
{
    for (int base = s; base < e; base += 64) {
        int cnt = e - base;
        if (cnt > 64) cnt = 64;
        int idxv = pool[base + min(lane, cnt - 1)];
        int t = 0;
        for (; t + 4 <= cnt; t += 4) {
            int s0 = __builtin_amdgcn_readlane(idxv, t);
            int s1 = __builtin_amdgcn_readlane(idxv, t + 1);
            int s2 = __builtin_amdgcn_readlane(idxv, t + 2);
            int s3 = __builtin_amdgcn_readlane(idxv, t + 3);
            unsigned short w0 = y[(long)s0 * 64 + lane];
            unsigned short w1 = y[(long)s1 * 64 + lane];
            unsigned short w2 = y[(long)s2 * 64 + lane];
            unsigned short w3 = y[(long)s3 * 64 + lane];
            accw(w0, acc); accw(w1, acc); accw(w2, acc); accw(w3, acc);
        }
        for (; t < cnt; t++) {
            int sid = __builtin_amdgcn_readlane(idxv, t);
            accw(y[(long)sid * 64 + lane], acc);
        }
    }
}

__global__ __launch_bounds__(256, 2) void fused_gnu_kernel(
    const int* __restrict__ rp, const int* __restrict__ pool,
    const unsigned short* __restrict__ y_dd,
    const unsigned short* __restrict__ y_pd,
    const unsigned short* __restrict__ y_dp,
    const float* __restrict__ x_drug, const float* __restrict__ x_prot,
    const bf16* __restrict__ Wdrug, const float* __restrict__ b_drug,
    const float* __restrict__ g_drug, const float* __restrict__ be_drug,
    const bf16* __restrict__ Wprot, const float* __restrict__ b_prot,
    const float* __restrict__ g_prot, const float* __restrict__ be_prot,
    float* __restrict__ out)
{
    __shared__ unsigned char ldsagg[128 * AGG_STRIDE];

    int blk = blockIdx.x;
    int wave = threadIdx.x >> 6;
    int lane = threadIdx.x & 63;
    bool isD = blk < NU_BD;
    int mb = (isD ? blk : blk - NU_BD) * 128;
    int M = isD ? ND : NP;

    // ---- phase A: gather this block's 128 nodes (32 per wave) into LDS ----
    for (int i = 0; i < 32; i++) {
        int node = mb + wave * 32 + i;
        if (node < M) {                       /* wave-uniform guard, no break */
            f32x2 r;
            if (isD) {
                int s1 = rp[node], e1 = rp[node + 1];
                int s2 = rp[ND + node], e2 = rp[ND + node + 1];
                f32x2 a; a.x = 0.f; a.y = 0.f;
                f32x2 b2; b2.x = 0.f; b2.y = 0.f;
                acc_seg(pool, s1, e1, y_dd, lane, &a);
                acc_seg(pool, s2, e2, y_pd, lane, &b2);
                float i1 = 0.5f / (float)max(e1 - s1, 1);
                float i2 = 0.5f / (float)max(e2 - s2, 1);
                r = a * i1 + b2 * i2;
            } else {
                int s1 = rp[2 * ND + node], e1 = rp[2 * ND + node + 1];
                f32x2 a; a.x = 0.f; a.y = 0.f;
                acc_seg(pool, s1, e1, y_dp, lane, &a);
                r = a * (1.0f / (float)max(e1 - s1, 1));
            }
            bf16x2 o; o[0] = (bf16)r.x; o[1] = (bf16)r.y;
            *(bf16x2*)(ldsagg + (wave * 32 + i) * AGG_STRIDE + lane * 4) = o;
        }
    }
    __syncthreads();

    // ---- phase B: GEMM K=256 (x || LDS agg) + bias+relu+residual+LN -------
    const float* x  = isD ? x_drug : x_prot;
    const bf16* W   = isD ? Wdrug : Wprot;
    const float* b  = isD ? b_drug : b_prot;
    const float* g  = isD ? g_drug : g_prot;
    const float* be = isD ? be_drug : be_prot;
    float* o        = isD ? out : out + (long)ND * D;

    int q = lane >> 4, c = lane & 15;
    int lcap = M - 1 - mb;                    /* max valid local row */

    f32x4 acc[2][8];
#pragma unroll
    for (int mt = 0; mt < 2; mt++)
#pragma unroll
        for (int nt = 0; nt < 8; nt++) acc[mt][nt] = 0;

#pragma unroll
    for (int kb = 0; kb < 8; kb++) {
        bf16x8 a[2];
#pragma unroll
        for (int mt = 0; mt < 2; mt++) {
            int lr = min(wave * 32 + mt * 16 + c, lcap);
            if (kb < 4)
                a[mt] = load_a_f32(x + (long)(mb + lr) * D + kb * 32 + q * 8);
            else
                a[mt] = *(const bf16x8*)(ldsagg + lr * AGG_STRIDE + (kb - 4) * 64 + q * 16);
        }
#pragma unroll
        for (int nt = 0; nt < 8; nt++) {
            bf16x8 bw = *(const bf16x8*)(W + (nt * 16 + c) * (2 * D) + kb * 32 + q * 8);
#pragma unroll
            for (int mt = 0; mt < 2; mt++)
                acc[mt][nt] = __builtin_amdgcn_mfma_f32_16x16x32_bf16(a[mt], bw, acc[mt][nt], 0, 0, 0);
        }
    }

    float bv[8], gv[8], bev[8];
#pragma unroll
    for (int nt = 0; nt < 8; nt++) {
        int col = nt * 16 + c;
        bv[nt] = b[col]; gv[nt] = g[col]; bev[nt] = be[col];
    }
#pragma unroll
    for (int mt = 0; mt < 2; mt++)
#pragma unroll
        for (int r = 0; r < 4; r++) {
            int row = mb + wave * 32 + mt * 16 + q * 4 + r;
            int rowc = min(row, M - 1);
            const float* xr = x + (long)rowc * D + c;
            float v[8];
            float sum = 0.f, sq = 0.f;
#pragma unroll
            for (int nt = 0; nt < 8; nt++) {
                float h = fmaxf(acc[mt][nt][r] + bv[nt], 0.f);
                float t = h + xr[nt * 16];
                v[nt] = t; sum += t; sq += t * t;
            }
#pragma unroll
            for (int m = 1; m < 16; m <<= 1) {
                sum += __shfl_xor(sum, m, 64);
                sq  += __shfl_xor(sq,  m, 64);
            }
            float mu   = sum * (1.f / 128.f);
            float var  = sq  * (1.f / 128.f) - mu * mu;
            float rstd = rsqrtf(var + 1e-5f);
            if (row < M) {
                float* op = o + (long)row * D + c;
#pragma unroll
                for (int nt = 0; nt < 8; nt++)
                    op[nt * 16] = (v[nt] - mu) * rstd * gv[nt] + bev[nt];
            }
        }
}

extern "C" void kernel_launch(void* const* d_in, const int* in_sizes, int n_in,
                              void* d_out, int out_size, void* d_ws, size_t ws_size,
                              hipStream_t stream)
{
    const float* x_drug  = (const float*)d_in[0];
    const float* x_prot  = (const float*)d_in[1];
    const float* Wagg_dd = (const float*)d_in[2];
    const float* Wagg_dp = (const float*)d_in[3];
    const float* Wagg_pd = (const float*)d_in[4];
    const float* W_drug  = (const float*)d_in[5];
    const float* b_drug  = (const float*)d_in[6];
    const float* W_prot  = (const float*)d_in[7];
    const float* b_prot  = (const float*)d_in[8];
    const float* g_drug  = (const float*)d_in[9];
    const float* be_drug = (const float*)d_in[10];
    const float* g_prot  = (const float*)d_in[11];
    const float* be_prot = (const float*)d_in[12];
    const int* dd_src = (const int*)d_in[13];
    const int* dd_dst = (const int*)d_in[14];
    const int* dp_src = (const int*)d_in[15];
    const int* dp_dst = (const int*)d_in[16];
    const int* pd_src = (const int*)d_in[17];
    const int* pd_dst = (const int*)d_in[18];

    char* ws = (char*)d_ws;
    bf16* Wdd   = (bf16*)(ws + OFF_WDD);
    bf16* Wdp   = (bf16*)(ws + OFF_WDP);
    bf16* Wpd   = (bf16*)(ws + OFF_WPD);
    bf16* Wdrug = (bf16*)(ws + OFF_WDRUG);
    bf16* Wprot = (bf16*)(ws + OFF_WPROT);
    unsigned char* y_dd = (unsigned char*)(ws + OFF_YDD);
    unsigned char* y_dp = (unsigned char*)(ws + OFF_YDP);
    unsigned char* y_pd = (unsigned char*)(ws + OFF_YPD);
    int* bcnt   = (int*)(ws + OFF_BCNT);
    int* gcur   = (int*)(ws + OFF_GCUR);
    int* cbase  = (int*)(ws + OFF_CBASE);
    int* rp     = (int*)(ws + OFF_RP);
    unsigned* pairs = (unsigned*)(ws + OFF_PAIRS);
    int* pool   = (int*)(ws + OFF_POOL);
    float* out  = (float*)d_out;

    // 0) zero coarse histogram (2KB)
    hipMemsetAsync(bcnt, 0, NBC * sizeof(int), stream);

    // 1) weights->bf16 (+K-permutation) || coarse histogram
    prep_kernel<<<dim3(128, 6), 256, 0, stream>>>(
        Wagg_dd, Wagg_dp, Wagg_pd, W_drug, W_prot,
        Wdd, Wdp, Wpd, Wdrug, Wprot,
        dd_dst, pd_dst, dp_dst, bcnt);

    // 2) exclusive scan of bucket counts
    scan_kernel<<<1, 256, 0, stream>>>(bcnt, cbase, gcur);

    // 3) coarse binning -> bucket-grouped packed pairs
    binA_kernel<<<NBLKA, 256, 0, stream>>>(
        dd_src, dd_dst, pd_src, pd_dst, dp_src, dp_dst, gcur, pairs);

    // 4) per-bucket counting sort -> pool + rp
    sortB_kernel<<<NBC, 256, 0, stream>>>(cbase, pairs, pool, rp);

    // 5) per-node transforms (fp8 y) -- right before the fused gather
    transform_kernel<<<TF_BD + TF_BP, 256, 0, stream>>>(
        x_drug, x_prot, Wdd, Wdp, Wpd, y_dd, y_dp, y_pd);

    // 6) fused gather (to LDS) + node update (GEMM + LN)
    fused_gnu_kernel<<<NU_BD + NU_BP, 256, 0, stream>>>(
        rp, pool,
        (const unsigned short*)y_dd, (const unsigned short*)y_pd,
        (const unsigned short*)y_dp,
        x_drug, x_prot,
        Wdrug, b_drug, g_drug, be_drug,
        Wprot, b_prot, g_prot, be_prot, out);
}

// Round 11
// 403.588 us; speedup vs baseline: 1.2662x; 1.2662x over previous
//
#include <hip/hip_runtime.h>

#define D 128
#define ND 100000
#define NP 50000
#define NE_DD 800000
#define NE_DP 600000
#define NE_PD 600000
#define NE_TOT 2000000

#define NTOT 250000      /* concatenated dst space: [dd:100k][pd:100k][dp:50k] */
#define NBC 490          /* coarse buckets, 512 nodes each (490*512 = 250880) */
#define NC 250880
#define CHUNKA 4096      /* edges per binning block (44KB LDS -> 3 blocks/CU) */
#define NBLKA 489        /* ceil(2M/4096) */
#define CHUNKIT 16       /* CHUNKA/256 */
#define SEGCAP 8192      /* max edges per coarse bucket (expected max ~6.6k) */

/* transform: drug waves do 32 rows (2 outputs), prot waves 64 rows */
#define TF_BD 782        /* ceil(100000/128) */
#define TF_BP 196        /* ceil(50000/256) */
/* node_update: every wave does 64 rows (M_rep=4) */
#define NU_BD 391        /* ceil(100000/256) */
#define NU_BP 196        /* ceil(50000/256) */

typedef __bf16 bf16;
typedef __attribute__((ext_vector_type(8))) __bf16 bf16x8;
typedef __attribute__((ext_vector_type(2))) __bf16 bf16x2;
typedef __attribute__((ext_vector_type(4))) float f32x4;
typedef __attribute__((ext_vector_type(2))) float f32x2;

// ---------------- workspace layout (byte offsets, 16B-aligned) -------------
#define OFF_WDD   0UL
#define OFF_WDP   32768UL
#define OFF_WPD   65536UL
#define OFF_WDRUG 98304UL
#define OFF_WPROT 163840UL
#define OFF_YDD   229376UL                      /* 100k x 128 bf16 */
#define OFF_YDP   (OFF_YDD + 25600000UL)        /* 100k x 128 bf16 */
#define OFF_YPD   (OFF_YDP + 25600000UL)        /* 50k x 128 bf16 */
#define OFF_AGGD  (OFF_YPD + 12800000UL)        /* 100k x 128 bf16 */
#define OFF_AGGP  (OFF_AGGD + 25600000UL)       /* 50k x 128 bf16 */
#define OFF_BCNT  (OFF_AGGP + 12800000UL)       /* NBC ints (zeroed in prep) */
#define OFF_GCUR  (OFF_BCNT + 2048UL)           /* NBC ints */
#define OFF_CBASE (OFF_GCUR + 2048UL)           /* NBC+1 ints */
#define OFF_RP    (OFF_CBASE + 2048UL)          /* NC ints (row ptrs) */
#define OFF_PAIRS (OFF_RP + 1003520UL)          /* 2M int2 (bucket-grouped) */
#define OFF_POOL  (OFF_PAIRS + 16000000UL)      /* 2M ints (node-grouped src) */

// ---------------- prep: weights->bf16  +  zero bcnt ------------------------
// W_drug / W_prot get their K in [128,256) columns permuted so that the agg
// half of the GEMM K-dim matches the permuted y/agg layout (position p holds
// original column (p%8)*16 + p/8).
__global__ __launch_bounds__(256) void prep_kernel(
    const float* __restrict__ w0, const float* __restrict__ w1,
    const float* __restrict__ w2, const float* __restrict__ w3,
    const float* __restrict__ w4,
    bf16* __restrict__ o0, bf16* __restrict__ o1, bf16* __restrict__ o2,
    bf16* __restrict__ o3, bf16* __restrict__ o4,
    int* __restrict__ bcnt)
{
    int m = blockIdx.y;
    int i = blockIdx.x * 256 + threadIdx.x;
    if (m == 5) {
        if (i < NBC) bcnt[i] = 0;
        return;
    }
    const float* src; bf16* dst; int n; bool perm;
    switch (m) {
        case 0: src = w0; dst = o0; n = D * D; perm = false; break;
        case 1: src = w1; dst = o1; n = D * D; perm = false; break;
        case 2: src = w2; dst = o2; n = D * D; perm = false; break;
        case 3: src = w3; dst = o3; n = D * 2 * D; perm = true; break;
        default: src = w4; dst = o4; n = D * 2 * D; perm = true; break;
    }
    if (i < n) {
        int si = i;
        if (perm) {
            int col = i & 255;
            if (col >= 128) {
                int p = col - 128;
                si = (i & ~255) | (128 + (p & 7) * 16 + (p >> 3));
            }
        }
        dst[i] = (bf16)src[si];
    }
}

// ---------------- per-node transforms: y = relu(x @ W^T) -------------------
// High arithmetic-intensity form: each wave owns M_rep 16-row tiles so W is
// read once per (16*M_rep) rows instead of once per 16.  y stored in permuted
// column order (position c*8+nt holds col nt*16+c) -> 1 coalesced 16B store.

__device__ __forceinline__ bf16x8 load_a_f32(const float* __restrict__ xr)
{
    float4 f0 = *(const float4*)xr;
    float4 f1 = *(const float4*)(xr + 4);
    bf16x8 a;
    a[0] = (bf16)f0.x; a[1] = (bf16)f0.y; a[2] = (bf16)f0.z; a[3] = (bf16)f0.w;
    a[4] = (bf16)f1.x; a[5] = (bf16)f1.y; a[6] = (bf16)f1.z; a[7] = (bf16)f1.w;
    return a;
}

__device__ __forceinline__ void transform_drug(
    const float* __restrict__ x, const bf16* __restrict__ W1,
    const bf16* __restrict__ W2, bf16* __restrict__ y1, bf16* __restrict__ y2,
    int blk)
{
    int lane = threadIdx.x & 63;
    int wave = threadIdx.x >> 6;
    int q = lane >> 4, c = lane & 15;
    int mb = blk * 128 + wave * 32;         /* 2 M-tiles per wave, 2 outputs */

    f32x4 acc1[2][8], acc2[2][8];
#pragma unroll
    for (int mt = 0; mt < 2; mt++)
#pragma unroll
        for (int nt = 0; nt < 8; nt++) { acc1[mt][nt] = 0; acc2[mt][nt] = 0; }

#pragma unroll
    for (int kb = 0; kb < 4; kb++) {
        int k = kb * 32 + q * 8;
        bf16x8 a[2];
#pragma unroll
        for (int mt = 0; mt < 2; mt++) {
            int row = min(mb + mt * 16 + c, ND - 1);
            a[mt] = load_a_f32(x + (long)row * D + k);
        }
#pragma unroll
        for (int nt = 0; nt < 8; nt++) {
            bf16x8 b1 = *(const bf16x8*)(W1 + (nt * 16 + c) * D + k);
            bf16x8 b2 = *(const bf16x8*)(W2 + (nt * 16 + c) * D + k);
#pragma unroll
            for (int mt = 0; mt < 2; mt++) {
                acc1[mt][nt] = __builtin_amdgcn_mfma_f32_16x16x32_bf16(a[mt], b1, acc1[mt][nt], 0, 0, 0);
                acc2[mt][nt] = __builtin_amdgcn_mfma_f32_16x16x32_bf16(a[mt], b2, acc2[mt][nt], 0, 0, 0);
            }
        }
    }
#pragma unroll
    for (int mt = 0; mt < 2; mt++)
#pragma unroll
        for (int r = 0; r < 4; r++) {
            int row = mb + mt * 16 + q * 4 + r;
            if (row < ND) {
                bf16x8 o1, o2;
#pragma unroll
                for (int nt = 0; nt < 8; nt++) {
                    o1[nt] = (bf16)fmaxf(acc1[mt][nt][r], 0.f);
                    o2[nt] = (bf16)fmaxf(acc2[mt][nt][r], 0.f);
                }
                *(bf16x8*)(y1 + (long)row * D + c * 8) = o1;
                *(bf16x8*)(y2 + (long)row * D + c * 8) = o2;
            }
        }
}

__device__ __forceinline__ void transform_prot(
    const float* __restrict__ x, const bf16* __restrict__ W1,
    bf16* __restrict__ y1, int blk)
{
    int lane = threadIdx.x & 63;
    int wave = threadIdx.x >> 6;
    int q = lane >> 4, c = lane & 15;
    int mb = blk * 256 + wave * 64;         /* 4 M-tiles per wave, 1 output */

    f32x4 acc[4][8];
#pragma unroll
    for (int mt = 0; mt < 4; mt++)
#pragma unroll
        for (int nt = 0; nt < 8; nt++) acc[mt][nt] = 0;

#pragma unroll
    for (int kb = 0; kb < 4; kb++) {
        int k = kb * 32 + q * 8;
        bf16x8 a[4];
#pragma unroll
        for (int mt = 0; mt < 4; mt++) {
            int row = min(mb + mt * 16 + c, NP - 1);
            a[mt] = load_a_f32(x + (long)row * D + k);
        }
#pragma unroll
        for (int nt = 0; nt < 8; nt++) {
            bf16x8 b1 = *(const bf16x8*)(W1 + (nt * 16 + c) * D + k);
#pragma unroll
            for (int mt = 0; mt < 4; mt++)
                acc[mt][nt] = __builtin_amdgcn_mfma_f32_16x16x32_bf16(a[mt], b1, acc[mt][nt], 0, 0, 0);
        }
    }
#pragma unroll
    for (int mt = 0; mt < 4; mt++)
#pragma unroll
        for (int r = 0; r < 4; r++) {
            int row = mb + mt * 16 + q * 4 + r;
            if (row < NP) {
                bf16x8 o1;
#pragma unroll
                for (int nt = 0; nt < 8; nt++)
                    o1[nt] = (bf16)fmaxf(acc[mt][nt][r], 0.f);
                *(bf16x8*)(y1 + (long)row * D + c * 8) = o1;
            }
        }
}

__global__ __launch_bounds__(256, 2) void transform_kernel(
    const float* __restrict__ x_drug, const float* __restrict__ x_prot,
    const bf16* __restrict__ Wdd, const bf16* __restrict__ Wdp,
    const bf16* __restrict__ Wpd,
    bf16* __restrict__ y_dd, bf16* __restrict__ y_dp, bf16* __restrict__ y_pd)
{
    int blk = blockIdx.x;
    if (blk < TF_BD)
        transform_drug(x_drug, Wdd, Wdp, y_dd, y_dp, blk);
    else
        transform_prot(x_prot, Wpd, y_pd, blk - TF_BD);
}

// ---------------- coarse histogram (LDS-staged) ----------------------------
__global__ __launch_bounds__(256) void hist_kernel(
    const int* __restrict__ dd_dst, const int* __restrict__ pd_dst,
    const int* __restrict__ dp_dst, int* __restrict__ bcnt)
{
    __shared__ int h[NBC];
    for (int i = threadIdx.x; i < NBC; i += 256) h[i] = 0;
    __syncthreads();
    int base = blockIdx.x * CHUNKA;
    for (int it = 0; it < CHUNKIT; it++) {
        int e = base + it * 256 + threadIdx.x;
        if (e < NE_TOT) {
            int didx;
            if (e < NE_DD) didx = dd_dst[e];
            else if (e < NE_DD + NE_PD) didx = ND + pd_dst[e - NE_DD];
            else didx = 2 * ND + dp_dst[e - NE_DD - NE_PD];
            atomicAdd(&h[didx >> 9], 1);
        }
    }
    __syncthreads();
    for (int i = threadIdx.x; i < NBC; i += 256)
        if (h[i]) atomicAdd(&bcnt[i], h[i]);
}

// ---------------- exclusive scan over 490 bucket counts (1 block) ----------
__global__ __launch_bounds__(256) void scan_kernel(
    const int* __restrict__ bcnt, int* __restrict__ cbase, int* __restrict__ gcur)
{
    __shared__ int ps[256];
    int t = threadIdx.x;
    int i0 = 2 * t, i1 = 2 * t + 1;
    int c0 = (i0 < NBC) ? bcnt[i0] : 0;
    int c1 = (i1 < NBC) ? bcnt[i1] : 0;
    ps[t] = c0 + c1;
    __syncthreads();
#pragma unroll
    for (int off = 1; off < 256; off <<= 1) {
        int add = (t >= off) ? ps[t - off] : 0;
        __syncthreads();
        ps[t] += add;
        __syncthreads();
    }
    int excl = ps[t] - (c0 + c1);
    if (i0 <= NBC) cbase[i0] = excl;            /* i0==NBC writes the sentinel */
    if (i0 < NBC) gcur[i0] = excl;
    if (i1 < NBC) { cbase[i1] = excl + c0; gcur[i1] = excl + c0; }
}

// ---------------- pass A: coarse binning with block-dense runs -------------
__global__ __launch_bounds__(256) void binA_kernel(
    const int* __restrict__ dd_src, const int* __restrict__ dd_dst,
    const int* __restrict__ pd_src, const int* __restrict__ pd_dst,
    const int* __restrict__ dp_src, const int* __restrict__ dp_dst,
    int* __restrict__ gcur, int2* __restrict__ pairs)
{
    __shared__ int h[NBC];
    __shared__ int gb[NBC];
    __shared__ int2 pr[CHUNKA];
    __shared__ unsigned short rk[CHUNKA];
    for (int i = threadIdx.x; i < NBC; i += 256) h[i] = 0;
    __syncthreads();
    int base = blockIdx.x * CHUNKA;
    for (int it = 0; it < CHUNKIT; it++) {
        int idx = it * 256 + threadIdx.x;
        int e = base + idx;
        int didx = -1, sv = 0;
        if (e < NE_TOT) {
            if (e < NE_DD) { didx = dd_dst[e]; sv = dd_src[e]; }
            else if (e < NE_DD + NE_PD) { int u = e - NE_DD; didx = ND + pd_dst[u]; sv = pd_src[u]; }
            else { int u = e - NE_DD - NE_PD; didx = 2 * ND + dp_dst[u]; sv = dp_src[u]; }
            rk[idx] = (unsigned short)atomicAdd(&h[didx >> 9], 1);
        }
        pr[idx] = make_int2(didx, sv);
    }
    __syncthreads();
    for (int b = threadIdx.x; b < NBC; b += 256) {
        int c = h[b];
        gb[b] = c ? atomicAdd(&gcur[b], c) : 0;
    }
    __syncthreads();
    for (int it = 0; it < CHUNKIT; it++) {
        int idx = it * 256 + threadIdx.x;
        int2 p = pr[idx];
        if (p.x >= 0) pairs[gb[p.x >> 9] + rk[idx]] = p;
    }
}

// ---------------- pass B: per-bucket LDS counting sort -> pool + rp --------
// LDS cut to 53KB (3 blocks/CU): pairs are re-read from L2 in the scatter
// pass instead of being staged in LDS.
__global__ __launch_bounds__(256) void sortB_kernel(
    const int* __restrict__ cbase, const int2* __restrict__ pairs,
    int* __restrict__ pool, int* __restrict__ rp)
{
    __shared__ int h[512];
    __shared__ int excl[512];
    __shared__ int ps[256];
    __shared__ unsigned short rk[SEGCAP];
    __shared__ int outl[SEGCAP];

    int b = blockIdx.x;
    int s0 = cbase[b], s1 = cbase[b + 1];
    int n = s1 - s0;
    if (n > SEGCAP) n = SEGCAP;   /* safety clamp; expected max ~6.6k */
    int t = threadIdx.x;
    h[t] = 0; h[t + 256] = 0;
    __syncthreads();

    for (int i = t; i < n; i += 256) {
        int2 p = pairs[s0 + i];
        rk[i] = (unsigned short)atomicAdd(&h[p.x & 511], 1);
    }
    __syncthreads();

    // exclusive scan over h[0..511] (2 elems per thread)
    int c0 = h[2 * t], c1 = h[2 * t + 1];
    ps[t] = c0 + c1;
    __syncthreads();
#pragma unroll
    for (int off = 1; off < 256; off <<= 1) {
        int add = (t >= off) ? ps[t - off] : 0;
        __syncthreads();
        ps[t] += add;
        __syncthreads();
    }
    int pe = ps[t] - (c0 + c1);
    excl[2 * t] = pe;
    excl[2 * t + 1] = pe + c0;
    __syncthreads();

    // row pointers for this bucket's 512 node slots
    int nb = b * 512;
    rp[nb + 2 * t] = s0 + excl[2 * t];
    rp[nb + 2 * t + 1] = s0 + excl[2 * t + 1];

    // LDS scatter (pairs re-read), then coalesced copy out
    for (int i = t; i < n; i += 256) {
        int2 p = pairs[s0 + i];
        outl[excl[p.x & 511] + rk[i]] = p.y;
    }
    __syncthreads();
    for (int i = t; i < n; i += 256)
        pool[s0 + i] = outl[i];
}

// ---------------- gather: one node per wave, 64 lanes x 4B -----------------
// Each lane owns 2 of the 128 (permuted) elements -> zero cross-lane
// reduction.  bf16->f32 via bit ops + packed f32x2 accumulate (3 VALU/edge
// floor).  Edge batches of 8 keep 8 independent 256B row-loads in flight.
__device__ __forceinline__ void acc2(unsigned u, f32x2* acc)
{
    union { unsigned u; float f; } lo, hi;
    lo.u = u << 16;
    hi.u = u & 0xFFFF0000u;
    f32x2 d; d.x = lo.f; d.y = hi.f;
    *acc += d;
}

__device__ __forceinline__ void acc_seg(
    const int* __restrict__ pool, int s, int e,
    const unsigned* __restrict__ y, int lane, f32x2* acc)
{
    int j = s;
    for (; j + 8 <= e; j += 8) {
        unsigned u[8];
#pragma unroll
        for (int t = 0; t < 8; t++)
            u[t] = y[(long)pool[j + t] * 64 + lane];
#pragma unroll
        for (int t = 0; t < 8; t++) acc2(u[t], acc);
    }
    if (j + 4 <= e) {
        unsigned u[4];
#pragma unroll
        for (int t = 0; t < 4; t++)
            u[t] = y[(long)pool[j + t] * 64 + lane];
#pragma unroll
        for (int t = 0; t < 4; t++) acc2(u[t], acc);
        j += 4;
    }
    if (j + 2 <= e) {
        unsigned u0 = y[(long)pool[j] * 64 + lane];
        unsigned u1 = y[(long)pool[j + 1] * 64 + lane];
        acc2(u0, acc); acc2(u1, acc);
        j += 2;
    }
    if (j < e)
        acc2(y[(long)pool[j] * 64 + lane], acc);
}

__global__ __launch_bounds__(256) void gather_kernel(
    const int* __restrict__ rp, const int* __restrict__ pool,
    const unsigned* __restrict__ y_dd, const unsigned* __restrict__ y_pd,
    const unsigned* __restrict__ y_dp,
    bf16* __restrict__ agg_d, bf16* __restrict__ agg_p)
{
    int wid = blockIdx.x * 4 + (threadIdx.x >> 6);
    int lane = threadIdx.x & 63;

    if (wid < ND) {
        int g = wid;
        int s1 = rp[g], e1 = rp[g + 1];
        int s2 = rp[ND + g], e2 = rp[ND + g + 1];
        f32x2 a; a.x = 0.f; a.y = 0.f;
        f32x2 b; b.x = 0.f; b.y = 0.f;
        acc_seg(pool, s1, e1, y_dd, lane, &a);
        acc_seg(pool, s2, e2, y_pd, lane, &b);
        float i1 = 0.5f / (float)max(e1 - s1, 1);
        float i2 = 0.5f / (float)max(e2 - s2, 1);
        f32x2 r = a * i1 + b * i2;
        bf16x2 o; o[0] = (bf16)r.x; o[1] = (bf16)r.y;
        *(bf16x2*)(agg_d + (long)g * D + lane * 2) = o;
    } else if (wid < ND + NP) {
        int p = wid - ND;
        int s1 = rp[2 * ND + p], e1 = rp[2 * ND + p + 1];
        f32x2 a; a.x = 0.f; a.y = 0.f;
        acc_seg(pool, s1, e1, y_dp, lane, &a);
        float i1 = 1.0f / (float)max(e1 - s1, 1);
        f32x2 r = a * i1;
        bf16x2 o; o[0] = (bf16)r.x; o[1] = (bf16)r.y;
        *(bf16x2*)(agg_p + (long)p * D + lane * 2) = o;
    }
}

// ---------------- fused node update: GEMM(K=256) + bias+relu+residual+LN ---
// M_rep=4: each wave owns 64 rows -> W read once per 64 rows (4x less L2
// traffic than per-16), 256 MFMAs per 112 VMEM loads, 4 independent M-tiles
// of ILP.  agg half of K consumes the permuted layout (W permuted in prep).
__device__ __forceinline__ void node_update_body(
    const float* __restrict__ x, const bf16* __restrict__ agg,
    const bf16* __restrict__ W, const float* __restrict__ b,
    const float* __restrict__ g, const float* __restrict__ be,
    float* __restrict__ out, int M, int blk)
{
    int lane = threadIdx.x & 63;
    int wave = threadIdx.x >> 6;
    int q = lane >> 4, c = lane & 15;
    int mb = blk * 256 + wave * 64;

    f32x4 acc[4][8];
#pragma unroll
    for (int mt = 0; mt < 4; mt++)
#pragma unroll
        for (int nt = 0; nt < 8; nt++) acc[mt][nt] = 0;

#pragma unroll
    for (int kb = 0; kb < 8; kb++) {
        bf16x8 a[4];
#pragma unroll
        for (int mt = 0; mt < 4; mt++) {
            int row = min(mb + mt * 16 + c, M - 1);
            if (kb < 4)
                a[mt] = load_a_f32(x + (long)row * D + kb * 32 + q * 8);
            else
                a[mt] = *(const bf16x8*)(agg + (long)row * D + (kb - 4) * 32 + q * 8);
        }
#pragma unroll
        for (int nt = 0; nt < 8; nt++) {
            bf16x8 bw = *(const bf16x8*)(W + (nt * 16 + c) * (2 * D) + kb * 32 + q * 8);
#pragma unroll
            for (int mt = 0; mt < 4; mt++)
                acc[mt][nt] = __builtin_amdgcn_mfma_f32_16x16x32_bf16(a[mt], bw, acc[mt][nt], 0, 0, 0);
        }
    }

    float bv[8], gv[8], bev[8];
#pragma unroll
    for (int nt = 0; nt < 8; nt++) {
        int col = nt * 16 + c;
        bv[nt] = b[col]; gv[nt] = g[col]; bev[nt] = be[col];
    }
#pragma unroll
    for (int mt = 0; mt < 4; mt++)
#pragma unroll
        for (int r = 0; r < 4; r++) {
            int row = mb + mt * 16 + q * 4 + r;
            int rowc = min(row, M - 1);
            const float* xr = x + (long)rowc * D + c;
            float v[8];
            float sum = 0.f, sq = 0.f;
#pragma unroll
            for (int nt = 0; nt < 8; nt++) {
                float h = fmaxf(acc[mt][nt][r] + bv[nt], 0.f);
                float t = h + xr[nt * 16];
                v[nt] = t; sum += t; sq += t * t;
            }
#pragma unroll
            for (int m = 1; m < 16; m <<= 1) {
                sum += __shfl_xor(sum, m, 64);
                sq  += __shfl_xor(sq,  m, 64);
            }
            float mu   = sum * (1.f / 128.f);
            float var  = sq  * (1.f / 128.f) - mu * mu;
            float rstd = rsqrtf(var + 1e-5f);
            if (row < M) {
                float* op = out + (long)row * D + c;
#pragma unroll
                for (int nt = 0; nt < 8; nt++)
                    op[nt * 16] = (v[nt] - mu) * rstd * gv[nt] + bev[nt];
            }
        }
}

__global__ __launch_bounds__(256, 2) void node_update_kernel(
    const float* __restrict__ x_drug, const float* __restrict__ x_prot,
    const bf16* __restrict__ agg_d, const bf16* __restrict__ agg_p,
    const bf16* __restrict__ Wdrug, const float* __restrict__ b_drug,
    const float* __restrict__ g_drug, const float* __restrict__ be_drug,
    const bf16* __restrict__ Wprot, const float* __restrict__ b_prot,
    const float* __restrict__ g_prot, const float* __restrict__ be_prot,
    float* __restrict__ out)
{
    int blk = blockIdx.x;
    if (blk < NU_BD)
        node_update_body(x_drug, agg_d, Wdrug, b_drug, g_drug, be_drug,
                         out, ND, blk);
    else
        node_update_body(x_prot, agg_p, Wprot, b_prot, g_prot, be_prot,
                         out + (long)ND * D, NP, blk - NU_BD);
}

extern "C" void kernel_launch(void* const* d_in, const int* in_sizes, int n_in,
                              void* d_out, int out_size, void* d_ws, size_t ws_size,
                              hipStream_t stream)
{
    const float* x_drug  = (const float*)d_in[0];
    const float* x_prot  = (const float*)d_in[1];
    const float* Wagg_dd = (const float*)d_in[2];
    const float* Wagg_dp = (const float*)d_in[3];
    const float* Wagg_pd = (const float*)d_in[4];
    const float* W_drug  = (const float*)d_in[5];
    const float* b_drug  = (const float*)d_in[6];
    const float* W_prot  = (const float*)d_in[7];
    const float* b_prot  = (const float*)d_in[8];
    const float* g_drug  = (const float*)d_in[9];
    const float* be_drug = (const float*)d_in[10];
    const float* g_prot  = (const float*)d_in[11];
    const float* be_prot = (const float*)d_in[12];
    const int* dd_src = (const int*)d_in[13];
    const int* dd_dst = (const int*)d_in[14];
    const int* dp_src = (const int*)d_in[15];
    const int* dp_dst = (const int*)d_in[16];
    const int* pd_src = (const int*)d_in[17];
    const int* pd_dst = (const int*)d_in[18];

    char* ws = (char*)d_ws;
    bf16* Wdd   = (bf16*)(ws + OFF_WDD);
    bf16* Wdp   = (bf16*)(ws + OFF_WDP);
    bf16* Wpd   = (bf16*)(ws + OFF_WPD);
    bf16* Wdrug = (bf16*)(ws + OFF_WDRUG);
    bf16* Wprot = (bf16*)(ws + OFF_WPROT);
    bf16* y_dd  = (bf16*)(ws + OFF_YDD);
    bf16* y_dp  = (bf16*)(ws + OFF_YDP);
    bf16* y_pd  = (bf16*)(ws + OFF_YPD);
    bf16* agg_d = (bf16*)(ws + OFF_AGGD);
    bf16* agg_p = (bf16*)(ws + OFF_AGGP);
    int* bcnt   = (int*)(ws + OFF_BCNT);
    int* gcur   = (int*)(ws + OFF_GCUR);
    int* cbase  = (int*)(ws + OFF_CBASE);
    int* rp     = (int*)(ws + OFF_RP);
    int2* pairs = (int2*)(ws + OFF_PAIRS);
    int* pool   = (int*)(ws + OFF_POOL);
    float* out  = (float*)d_out;

    // 1) weights->bf16 (+K-permutation for node-update W) + zero histogram
    prep_kernel<<<dim3(128, 6), 256, 0, stream>>>(
        Wagg_dd, Wagg_dp, Wagg_pd, W_drug, W_prot,
        Wdd, Wdp, Wpd, Wdrug, Wprot, bcnt);

    // 2) per-node transforms (drug: dd+dp, prot: pd)
    transform_kernel<<<TF_BD + TF_BP, 256, 0, stream>>>(
        x_drug, x_prot, Wdd, Wdp, Wpd, y_dd, y_dp, y_pd);

    // 3) two-level counting sort of edges by destination
    hist_kernel<<<NBLKA, 256, 0, stream>>>(dd_dst, pd_dst, dp_dst, bcnt);
    scan_kernel<<<1, 256, 0, stream>>>(bcnt, cbase, gcur);
    binA_kernel<<<NBLKA, 256, 0, stream>>>(
        dd_src, dd_dst, pd_src, pd_dst, dp_src, dp_dst, gcur, pairs);
    sortB_kernel<<<NBC, 256, 0, stream>>>(cbase, pairs, pool, rp);

    // 4) gather + per-relation mean (one node per wave, 64x4B lanes)
    gather_kernel<<<(ND + NP + 3) / 4, 256, 0, stream>>>(
        rp, pool, (const unsigned*)y_dd, (const unsigned*)y_pd,
        (const unsigned*)y_dp, agg_d, agg_p);

    // 5) fused node updates (drug rows then prot rows of out)
    node_update_kernel<<<NU_BD + NU_BP, 256, 0, stream>>>(
        x_drug, x_prot, agg_d, agg_p,
        Wdrug, b_drug, g_drug, be_drug,
        Wprot, b_prot, g_prot, be_prot, out);
}

// Round 12
// 400.553 us; speedup vs baseline: 1.2758x; 1.0076x over previous
//
#include <hip/hip_runtime.h>

#define D 128
#define ND 100000
#define NP 50000
#define NE_DD 800000
#define NE_DP 600000
#define NE_PD 600000
#define NE_TOT 2000000

#define NTOT 250000      /* concatenated dst space: [dd:100k][pd:100k][dp:50k] */
#define NBC 490          /* coarse buckets, 512 nodes each (490*512 = 250880) */
#define NC 250880
#define CHUNKA 4096      /* edges per binning block (44KB LDS -> 3 blocks/CU) */
#define NBLKA 489        /* ceil(2M/4096) */
#define CHUNKIT 16       /* CHUNKA/256 */
#define SEGCAP 8192      /* max edges per coarse bucket (expected max ~6.6k) */

/* transform: drug waves do 32 rows (2 outputs), prot waves 64 rows */
#define TF_BD 782        /* ceil(100000/128) */
#define TF_BP 196        /* ceil(50000/256) */
/* node_update: every wave does 64 rows (M_rep=4) */
#define NU_BD 391        /* ceil(100000/256) */
#define NU_BP 196        /* ceil(50000/256) */

typedef __bf16 bf16;
typedef __attribute__((ext_vector_type(8))) __bf16 bf16x8;
typedef __attribute__((ext_vector_type(2))) __bf16 bf16x2;
typedef __attribute__((ext_vector_type(4))) float f32x4;
typedef __attribute__((ext_vector_type(2))) float f32x2;

// ---------------- workspace layout (byte offsets, 16B-aligned) -------------
#define OFF_WDD   0UL
#define OFF_WDP   32768UL
#define OFF_WPD   65536UL
#define OFF_WDRUG 98304UL
#define OFF_WPROT 163840UL
#define OFF_YDD   229376UL                      /* 100k x 128 bf16 */
#define OFF_YDP   (OFF_YDD + 25600000UL)        /* 100k x 128 bf16 */
#define OFF_YPD   (OFF_YDP + 25600000UL)        /* 50k x 128 bf16 */
#define OFF_AGGD  (OFF_YPD + 12800000UL)        /* 100k x 128 bf16 */
#define OFF_AGGP  (OFF_AGGD + 25600000UL)       /* 50k x 128 bf16 */
#define OFF_BCNT  (OFF_AGGP + 12800000UL)       /* NBC ints (zeroed in prep) */
#define OFF_GCUR  (OFF_BCNT + 2048UL)           /* NBC ints */
#define OFF_CBASE (OFF_GCUR + 2048UL)           /* NBC+1 ints */
#define OFF_RP    (OFF_CBASE + 2048UL)          /* NC ints (row ptrs) */
#define OFF_PAIRS (OFF_RP + 1003520UL)          /* 2M u32 packed (ldst<<17|src) */
#define OFF_POOL  (OFF_PAIRS + 16000000UL)      /* 2M ints (node-grouped src) */

// ---------------- prep: weights->bf16  +  zero bcnt ------------------------
// W_drug / W_prot get their K in [128,256) columns permuted so that the agg
// half of the GEMM K-dim matches the permuted y/agg layout (position p holds
// original column (p%8)*16 + p/8).
__global__ __launch_bounds__(256) void prep_kernel(
    const float* __restrict__ w0, const float* __restrict__ w1,
    const float* __restrict__ w2, const float* __restrict__ w3,
    const float* __restrict__ w4,
    bf16* __restrict__ o0, bf16* __restrict__ o1, bf16* __restrict__ o2,
    bf16* __restrict__ o3, bf16* __restrict__ o4,
    int* __restrict__ bcnt)
{
    int m = blockIdx.y;
    int i = blockIdx.x * 256 + threadIdx.x;
    if (m == 5) {
        if (i < NBC) bcnt[i] = 0;
        return;
    }
    const float* src; bf16* dst; int n; bool perm;
    switch (m) {
        case 0: src = w0; dst = o0; n = D * D; perm = false; break;
        case 1: src = w1; dst = o1; n = D * D; perm = false; break;
        case 2: src = w2; dst = o2; n = D * D; perm = false; break;
        case 3: src = w3; dst = o3; n = D * 2 * D; perm = true; break;
        default: src = w4; dst = o4; n = D * 2 * D; perm = true; break;
    }
    if (i < n) {
        int si = i;
        if (perm) {
            int col = i & 255;
            if (col >= 128) {
                int p = col - 128;
                si = (i & ~255) | (128 + (p & 7) * 16 + (p >> 3));
            }
        }
        dst[i] = (bf16)src[si];
    }
}

// ---------------- per-node transforms: y = relu(x @ W^T) -------------------
__device__ __forceinline__ bf16x8 load_a_f32(const float* __restrict__ xr)
{
    float4 f0 = *(const float4*)xr;
    float4 f1 = *(const float4*)(xr + 4);
    bf16x8 a;
    a[0] = (bf16)f0.x; a[1] = (bf16)f0.y; a[2] = (bf16)f0.z; a[3] = (bf16)f0.w;
    a[4] = (bf16)f1.x; a[5] = (bf16)f1.y; a[6] = (bf16)f1.z; a[7] = (bf16)f1.w;
    return a;
}

__device__ __forceinline__ void transform_drug(
    const float* __restrict__ x, const bf16* __restrict__ W1,
    const bf16* __restrict__ W2, bf16* __restrict__ y1, bf16* __restrict__ y2,
    int blk)
{
    int lane = threadIdx.x & 63;
    int wave = threadIdx.x >> 6;
    int q = lane >> 4, c = lane & 15;
    int mb = blk * 128 + wave * 32;         /* 2 M-tiles per wave, 2 outputs */

    f32x4 acc1[2][8], acc2[2][8];
#pragma unroll
    for (int mt = 0; mt < 2; mt++)
#pragma unroll
        for (int nt = 0; nt < 8; nt++) { acc1[mt][nt] = 0; acc2[mt][nt] = 0; }

#pragma unroll
    for (int kb = 0; kb < 4; kb++) {
        int k = kb * 32 + q * 8;
        bf16x8 a[2];
#pragma unroll
        for (int mt = 0; mt < 2; mt++) {
            int row = min(mb + mt * 16 + c, ND - 1);
            a[mt] = load_a_f32(x + (long)row * D + k);
        }
#pragma unroll
        for (int nt = 0; nt < 8; nt++) {
            bf16x8 b1 = *(const bf16x8*)(W1 + (nt * 16 + c) * D + k);
            bf16x8 b2 = *(const bf16x8*)(W2 + (nt * 16 + c) * D + k);
#pragma unroll
            for (int mt = 0; mt < 2; mt++) {
                acc1[mt][nt] = __builtin_amdgcn_mfma_f32_16x16x32_bf16(a[mt], b1, acc1[mt][nt], 0, 0, 0);
                acc2[mt][nt] = __builtin_amdgcn_mfma_f32_16x16x32_bf16(a[mt], b2, acc2[mt][nt], 0, 0, 0);
            }
        }
    }
#pragma unroll
    for (int mt = 0; mt < 2; mt++)
#pragma unroll
        for (int r = 0; r < 4; r++) {
            int row = mb + mt * 16 + q * 4 + r;
            if (row < ND) {
                bf16x8 o1, o2;
#pragma unroll
                for (int nt = 0; nt < 8; nt++) {
                    o1[nt] = (bf16)fmaxf(acc1[mt][nt][r], 0.f);
                    o2[nt] = (bf16)fmaxf(acc2[mt][nt][r], 0.f);
                }
                *(bf16x8*)(y1 + (long)row * D + c * 8) = o1;
                *(bf16x8*)(y2 + (long)row * D + c * 8) = o2;
            }
        }
}

__device__ __forceinline__ void transform_prot(
    const float* __restrict__ x, const bf16* __restrict__ W1,
    bf16* __restrict__ y1, int blk)
{
    int lane = threadIdx.x & 63;
    int wave = threadIdx.x >> 6;
    int q = lane >> 4, c = lane & 15;
    int mb = blk * 256 + wave * 64;         /* 4 M-tiles per wave, 1 output */

    f32x4 acc[4][8];
#pragma unroll
    for (int mt = 0; mt < 4; mt++)
#pragma unroll
        for (int nt = 0; nt < 8; nt++) acc[mt][nt] = 0;

#pragma unroll
    for (int kb = 0; kb < 4; kb++) {
        int k = kb * 32 + q * 8;
        bf16x8 a[4];
#pragma unroll
        for (int mt = 0; mt < 4; mt++) {
            int row = min(mb + mt * 16 + c, NP - 1);
            a[mt] = load_a_f32(x + (long)row * D + k);
        }
#pragma unroll
        for (int nt = 0; nt < 8; nt++) {
            bf16x8 b1 = *(const bf16x8*)(W1 + (nt * 16 + c) * D + k);
#pragma unroll
            for (int mt = 0; mt < 4; mt++)
                acc[mt][nt] = __builtin_amdgcn_mfma_f32_16x16x32_bf16(a[mt], b1, acc[mt][nt], 0, 0, 0);
        }
    }
#pragma unroll
    for (int mt = 0; mt < 4; mt++)
#pragma unroll
        for (int r = 0; r < 4; r++) {
            int row = mb + mt * 16 + q * 4 + r;
            if (row < NP) {
                bf16x8 o1;
#pragma unroll
                for (int nt = 0; nt < 8; nt++)
                    o1[nt] = (bf16)fmaxf(acc[mt][nt][r], 0.f);
                *(bf16x8*)(y1 + (long)row * D + c * 8) = o1;
            }
        }
}

__global__ __launch_bounds__(256, 2) void transform_kernel(
    const float* __restrict__ x_drug, const float* __restrict__ x_prot,
    const bf16* __restrict__ Wdd, const bf16* __restrict__ Wdp,
    const bf16* __restrict__ Wpd,
    bf16* __restrict__ y_dd, bf16* __restrict__ y_dp, bf16* __restrict__ y_pd)
{
    int blk = blockIdx.x;
    if (blk < TF_BD)
        transform_drug(x_drug, Wdd, Wdp, y_dd, y_dp, blk);
    else
        transform_prot(x_prot, Wpd, y_pd, blk - TF_BD);
}

// ---------------- coarse histogram (LDS-staged) ----------------------------
__global__ __launch_bounds__(256) void hist_kernel(
    const int* __restrict__ dd_dst, const int* __restrict__ pd_dst,
    const int* __restrict__ dp_dst, int* __restrict__ bcnt)
{
    __shared__ int h[NBC];
    for (int i = threadIdx.x; i < NBC; i += 256) h[i] = 0;
    __syncthreads();
    int base = blockIdx.x * CHUNKA;
    for (int it = 0; it < CHUNKIT; it++) {
        int e = base + it * 256 + threadIdx.x;
        if (e < NE_TOT) {
            int didx;
            if (e < NE_DD) didx = dd_dst[e];
            else if (e < NE_DD + NE_PD) didx = ND + pd_dst[e - NE_DD];
            else didx = 2 * ND + dp_dst[e - NE_DD - NE_PD];
            atomicAdd(&h[didx >> 9], 1);
        }
    }
    __syncthreads();
    for (int i = threadIdx.x; i < NBC; i += 256)
        if (h[i]) atomicAdd(&bcnt[i], h[i]);
}

// ---------------- exclusive scan over 490 bucket counts (1 block) ----------
__global__ __launch_bounds__(256) void scan_kernel(
    const int* __restrict__ bcnt, int* __restrict__ cbase, int* __restrict__ gcur)
{
    __shared__ int ps[256];
    int t = threadIdx.x;
    int i0 = 2 * t, i1 = 2 * t + 1;
    int c0 = (i0 < NBC) ? bcnt[i0] : 0;
    int c1 = (i1 < NBC) ? bcnt[i1] : 0;
    ps[t] = c0 + c1;
    __syncthreads();
#pragma unroll
    for (int off = 1; off < 256; off <<= 1) {
        int add = (t >= off) ? ps[t - off] : 0;
        __syncthreads();
        ps[t] += add;
        __syncthreads();
    }
    int excl = ps[t] - (c0 + c1);
    if (i0 <= NBC) cbase[i0] = excl;            /* i0==NBC writes the sentinel */
    if (i0 < NBC) gcur[i0] = excl;
    if (i1 < NBC) { cbase[i1] = excl + c0; gcur[i1] = excl + c0; }
}

// ---------------- pass A: coarse binning, packed u32 output ----------------
// pairs packed as (local_dst<<17 | src): src < 2^17, local_dst < 512.
// Halves pair traffic (binA write 16->8 MB, sortB reads 32->16 MB).
__global__ __launch_bounds__(256) void binA_kernel(
    const int* __restrict__ dd_src, const int* __restrict__ dd_dst,
    const int* __restrict__ pd_src, const int* __restrict__ pd_dst,
    const int* __restrict__ dp_src, const int* __restrict__ dp_dst,
    int* __restrict__ gcur, unsigned* __restrict__ pairs)
{
    __shared__ int h[NBC];
    __shared__ int gb[NBC];
    __shared__ int2 pr[CHUNKA];
    __shared__ unsigned short rk[CHUNKA];
    for (int i = threadIdx.x; i < NBC; i += 256) h[i] = 0;
    __syncthreads();
    int base = blockIdx.x * CHUNKA;
    for (int it = 0; it < CHUNKIT; it++) {
        int idx = it * 256 + threadIdx.x;
        int e = base + idx;
        int didx = -1, sv = 0;
        if (e < NE_TOT) {
            if (e < NE_DD) { didx = dd_dst[e]; sv = dd_src[e]; }
            else if (e < NE_DD + NE_PD) { int u = e - NE_DD; didx = ND + pd_dst[u]; sv = pd_src[u]; }
            else { int u = e - NE_DD - NE_PD; didx = 2 * ND + dp_dst[u]; sv = dp_src[u]; }
            rk[idx] = (unsigned short)atomicAdd(&h[didx >> 9], 1);
        }
        pr[idx] = make_int2(didx, sv);
    }
    __syncthreads();
    for (int b = threadIdx.x; b < NBC; b += 256) {
        int c = h[b];
        gb[b] = c ? atomicAdd(&gcur[b], c) : 0;
    }
    __syncthreads();
    for (int it = 0; it < CHUNKIT; it++) {
        int idx = it * 256 + threadIdx.x;
        int2 p = pr[idx];
        if (p.x >= 0)
            pairs[gb[p.x >> 9] + rk[idx]] =
                ((unsigned)(p.x & 511) << 17) | (unsigned)p.y;
    }
}

// ---------------- pass B: per-bucket LDS counting sort -> pool + rp --------
__global__ __launch_bounds__(256) void sortB_kernel(
    const int* __restrict__ cbase, const unsigned* __restrict__ pairs,
    int* __restrict__ pool, int* __restrict__ rp)
{
    __shared__ int h[512];
    __shared__ int excl[512];
    __shared__ int ps[256];
    __shared__ unsigned short rk[SEGCAP];
    __shared__ int outl[SEGCAP];

    int b = blockIdx.x;
    int s0 = cbase[b], s1 = cbase[b + 1];
    int n = s1 - s0;
    if (n > SEGCAP) n = SEGCAP;   /* safety clamp; expected max ~6.6k */
    int t = threadIdx.x;
    h[t] = 0; h[t + 256] = 0;
    __syncthreads();

    for (int i = t; i < n; i += 256) {
        unsigned p = pairs[s0 + i];
        rk[i] = (unsigned short)atomicAdd(&h[p >> 17], 1);
    }
    __syncthreads();

    // exclusive scan over h[0..511] (2 elems per thread)
    int c0 = h[2 * t], c1 = h[2 * t + 1];
    ps[t] = c0 + c1;
    __syncthreads();
#pragma unroll
    for (int off = 1; off < 256; off <<= 1) {
        int add = (t >= off) ? ps[t - off] : 0;
        __syncthreads();
        ps[t] += add;
        __syncthreads();
    }
    int pe = ps[t] - (c0 + c1);
    excl[2 * t] = pe;
    excl[2 * t + 1] = pe + c0;
    __syncthreads();

    // row pointers for this bucket's 512 node slots
    int nb = b * 512;
    rp[nb + 2 * t] = s0 + excl[2 * t];
    rp[nb + 2 * t + 1] = s0 + excl[2 * t + 1];

    // LDS scatter (pairs re-read), then coalesced copy out
    for (int i = t; i < n; i += 256) {
        unsigned p = pairs[s0 + i];
        outl[excl[p >> 17] + rk[i]] = (int)(p & 0x1FFFFu);
    }
    __syncthreads();
    for (int i = t; i < n; i += 256)
        pool[s0 + i] = outl[i];
}

// ---------------- gather: one node per wave, 64 lanes x 4B -----------------
// Drug nodes interleave their dd and pd segments (4+4 loads in flight) to
// overlap the two otherwise-serial latency chains.  Per-segment accumulation
// order unchanged -> bit-identical output.
__device__ __forceinline__ void acc2(unsigned u, f32x2* acc)
{
    union { unsigned u; float f; } lo, hi;
    lo.u = u << 16;
    hi.u = u & 0xFFFF0000u;
    f32x2 d; d.x = lo.f; d.y = hi.f;
    *acc += d;
}

__device__ __forceinline__ void acc_seg(
    const int* __restrict__ pool, int s, int e,
    const unsigned* __restrict__ y, int lane, f32x2* acc)
{
    int j = s;
    for (; j + 8 <= e; j += 8) {
        unsigned u[8];
#pragma unroll
        for (int t = 0; t < 8; t++)
            u[t] = y[(long)pool[j + t] * 64 + lane];
#pragma unroll
        for (int t = 0; t < 8; t++) acc2(u[t], acc);
    }
    if (j + 4 <= e) {
        unsigned u[4];
#pragma unroll
        for (int t = 0; t < 4; t++)
            u[t] = y[(long)pool[j + t] * 64 + lane];
#pragma unroll
        for (int t = 0; t < 4; t++) acc2(u[t], acc);
        j += 4;
    }
    if (j + 2 <= e) {
        unsigned u0 = y[(long)pool[j] * 64 + lane];
        unsigned u1 = y[(long)pool[j + 1] * 64 + lane];
        acc2(u0, acc); acc2(u1, acc);
        j += 2;
    }
    if (j < e)
        acc2(y[(long)pool[j] * 64 + lane], acc);
}

__global__ __launch_bounds__(256) void gather_kernel(
    const int* __restrict__ rp, const int* __restrict__ pool,
    const unsigned* __restrict__ y_dd, const unsigned* __restrict__ y_pd,
    const unsigned* __restrict__ y_dp,
    bf16* __restrict__ agg_d, bf16* __restrict__ agg_p)
{
    int wid = blockIdx.x * 4 + (threadIdx.x >> 6);
    int lane = threadIdx.x & 63;

    if (wid < ND) {
        int g = wid;
        int s1 = rp[g], e1 = rp[g + 1];
        int s2 = rp[ND + g], e2 = rp[ND + g + 1];
        f32x2 a; a.x = 0.f; a.y = 0.f;
        f32x2 b; b.x = 0.f; b.y = 0.f;
        int j1 = s1, j2 = s2;
        // interleaved 4+4: both segments' loads in flight together
        while (j1 + 4 <= e1 && j2 + 4 <= e2) {
            unsigned ua[4], ub[4];
#pragma unroll
            for (int t = 0; t < 4; t++)
                ua[t] = y_dd[(long)pool[j1 + t] * 64 + lane];
#pragma unroll
            for (int t = 0; t < 4; t++)
                ub[t] = y_pd[(long)pool[j2 + t] * 64 + lane];
#pragma unroll
            for (int t = 0; t < 4; t++) acc2(ua[t], &a);
#pragma unroll
            for (int t = 0; t < 4; t++) acc2(ub[t], &b);
            j1 += 4; j2 += 4;
        }
        acc_seg(pool, j1, e1, y_dd, lane, &a);
        acc_seg(pool, j2, e2, y_pd, lane, &b);
        float i1 = 0.5f / (float)max(e1 - s1, 1);
        float i2 = 0.5f / (float)max(e2 - s2, 1);
        f32x2 r = a * i1 + b * i2;
        bf16x2 o; o[0] = (bf16)r.x; o[1] = (bf16)r.y;
        *(bf16x2*)(agg_d + (long)g * D + lane * 2) = o;
    } else if (wid < ND + NP) {
        int p = wid - ND;
        int s1 = rp[2 * ND + p], e1 = rp[2 * ND + p + 1];
        f32x2 a; a.x = 0.f; a.y = 0.f;
        acc_seg(pool, s1, e1, y_dp, lane, &a);
        float i1 = 1.0f / (float)max(e1 - s1, 1);
        f32x2 r = a * i1;
        bf16x2 o; o[0] = (bf16)r.x; o[1] = (bf16)r.y;
        *(bf16x2*)(agg_p + (long)p * D + lane * 2) = o;
    }
}

// ---------------- fused node update: GEMM(K=256) + bias+relu+residual+LN ---
__device__ __forceinline__ void node_update_body(
    const float* __restrict__ x, const bf16* __restrict__ agg,
    const bf16* __restrict__ W, const float* __restrict__ b,
    const float* __restrict__ g, const float* __restrict__ be,
    float* __restrict__ out, int M, int blk)
{
    int lane = threadIdx.x & 63;
    int wave = threadIdx.x >> 6;
    int q = lane >> 4, c = lane & 15;
    int mb = blk * 256 + wave * 64;

    f32x4 acc[4][8];
#pragma unroll
    for (int mt = 0; mt < 4; mt++)
#pragma unroll
        for (int nt = 0; nt < 8; nt++) acc[mt][nt] = 0;

#pragma unroll
    for (int kb = 0; kb < 8; kb++) {
        bf16x8 a[4];
#pragma unroll
        for (int mt = 0; mt < 4; mt++) {
            int row = min(mb + mt * 16 + c, M - 1);
            if (kb < 4)
                a[mt] = load_a_f32(x + (long)row * D + kb * 32 + q * 8);
            else
                a[mt] = *(const bf16x8*)(agg + (long)row * D + (kb - 4) * 32 + q * 8);
        }
#pragma unroll
        for (int nt = 0; nt < 8; nt++) {
            bf16x8 bw = *(const bf16x8*)(W + (nt * 16 + c) * (2 * D) + kb * 32 + q * 8);
#pragma unroll
            for (int mt = 0; mt < 4; mt++)
                acc[mt][nt] = __builtin_amdgcn_mfma_f32_16x16x32_bf16(a[mt], bw, acc[mt][nt], 0, 0, 0);
        }
    }

    float bv[8], gv[8], bev[8];
#pragma unroll
    for (int nt = 0; nt < 8; nt++) {
        int col = nt * 16 + c;
        bv[nt] = b[col]; gv[nt] = g[col]; bev[nt] = be[col];
    }
#pragma unroll
    for (int mt = 0; mt < 4; mt++)
#pragma unroll
        for (int r = 0; r < 4; r++) {
            int row = mb + mt * 16 + q * 4 + r;
            int rowc = min(row, M - 1);
            const float* xr = x + (long)rowc * D + c;
            float v[8];
            float sum = 0.f, sq = 0.f;
#pragma unroll
            for (int nt = 0; nt < 8; nt++) {
                float h = fmaxf(acc[mt][nt][r] + bv[nt], 0.f);
                float t = h + xr[nt * 16];
                v[nt] = t; sum += t; sq += t * t;
            }
#pragma unroll
            for (int m = 1; m < 16; m <<= 1) {
                sum += __shfl_xor(sum, m, 64);
                sq  += __shfl_xor(sq,  m, 64);
            }
            float mu   = sum * (1.f / 128.f);
            float var  = sq  * (1.f / 128.f) - mu * mu;
            float rstd = rsqrtf(var + 1e-5f);
            if (row < M) {
                float* op = out + (long)row * D + c;
#pragma unroll
                for (int nt = 0; nt < 8; nt++)
                    op[nt * 16] = (v[nt] - mu) * rstd * gv[nt] + bev[nt];
            }
        }
}

__global__ __launch_bounds__(256, 2) void node_update_kernel(
    const float* __restrict__ x_drug, const float* __restrict__ x_prot,
    const bf16* __restrict__ agg_d, const bf16* __restrict__ agg_p,
    const bf16* __restrict__ Wdrug, const float* __restrict__ b_drug,
    const float* __restrict__ g_drug, const float* __restrict__ be_drug,
    const bf16* __restrict__ Wprot, const float* __restrict__ b_prot,
    const float* __restrict__ g_prot, const float* __restrict__ be_prot,
    float* __restrict__ out)
{
    int blk = blockIdx.x;
    if (blk < NU_BD)
        node_update_body(x_drug, agg_d, Wdrug, b_drug, g_drug, be_drug,
                         out, ND, blk);
    else
        node_update_body(x_prot, agg_p, Wprot, b_prot, g_prot, be_prot,
                         out + (long)ND * D, NP, blk - NU_BD);
}

extern "C" void kernel_launch(void* const* d_in, const int* in_sizes, int n_in,
                              void* d_out, int out_size, void* d_ws, size_t ws_size,
                              hipStream_t stream)
{
    const float* x_drug  = (const float*)d_in[0];
    const float* x_prot  = (const float*)d_in[1];
    const float* Wagg_dd = (const float*)d_in[2];
    const float* Wagg_dp = (const float*)d_in[3];
    const float* Wagg_pd = (const float*)d_in[4];
    const float* W_drug  = (const float*)d_in[5];
    const float* b_drug  = (const float*)d_in[6];
    const float* W_prot  = (const float*)d_in[7];
    const float* b_prot  = (const float*)d_in[8];
    const float* g_drug  = (const float*)d_in[9];
    const float* be_drug = (const float*)d_in[10];
    const float* g_prot  = (const float*)d_in[11];
    const float* be_prot = (const float*)d_in[12];
    const int* dd_src = (const int*)d_in[13];
    const int* dd_dst = (const int*)d_in[14];
    const int* dp_src = (const int*)d_in[15];
    const int* dp_dst = (const int*)d_in[16];
    const int* pd_src = (const int*)d_in[17];
    const int* pd_dst = (const int*)d_in[18];

    char* ws = (char*)d_ws;
    bf16* Wdd   = (bf16*)(ws + OFF_WDD);
    bf16* Wdp   = (bf16*)(ws + OFF_WDP);
    bf16* Wpd   = (bf16*)(ws + OFF_WPD);
    bf16* Wdrug = (bf16*)(ws + OFF_WDRUG);
    bf16* Wprot = (bf16*)(ws + OFF_WPROT);
    bf16* y_dd  = (bf16*)(ws + OFF_YDD);
    bf16* y_dp  = (bf16*)(ws + OFF_YDP);
    bf16* y_pd  = (bf16*)(ws + OFF_YPD);
    bf16* agg_d = (bf16*)(ws + OFF_AGGD);
    bf16* agg_p = (bf16*)(ws + OFF_AGGP);
    int* bcnt   = (int*)(ws + OFF_BCNT);
    int* gcur   = (int*)(ws + OFF_GCUR);
    int* cbase  = (int*)(ws + OFF_CBASE);
    int* rp     = (int*)(ws + OFF_RP);
    unsigned* pairs = (unsigned*)(ws + OFF_PAIRS);
    int* pool   = (int*)(ws + OFF_POOL);
    float* out  = (float*)d_out;

    // 1) weights->bf16 (+K-permutation for node-update W) + zero histogram
    prep_kernel<<<dim3(128, 6), 256, 0, stream>>>(
        Wagg_dd, Wagg_dp, Wagg_pd, W_drug, W_prot,
        Wdd, Wdp, Wpd, Wdrug, Wprot, bcnt);

    // 2) per-node transforms (drug: dd+dp, prot: pd)
    transform_kernel<<<TF_BD + TF_BP, 256, 0, stream>>>(
        x_drug, x_prot, Wdd, Wdp, Wpd, y_dd, y_dp, y_pd);

    // 3) two-level counting sort of edges by destination (packed u32 pairs)
    hist_kernel<<<NBLKA, 256, 0, stream>>>(dd_dst, pd_dst, dp_dst, bcnt);
    scan_kernel<<<1, 256, 0, stream>>>(bcnt, cbase, gcur);
    binA_kernel<<<NBLKA, 256, 0, stream>>>(
        dd_src, dd_dst, pd_src, pd_dst, dp_src, dp_dst, gcur, pairs);
    sortB_kernel<<<NBC, 256, 0, stream>>>(cbase, pairs, pool, rp);

    // 4) gather + per-relation mean (one node per wave, segment-interleaved)
    gather_kernel<<<(ND + NP + 3) / 4, 256, 0, stream>>>(
        rp, pool, (const unsigned*)y_dd, (const unsigned*)y_pd,
        (const unsigned*)y_dp, agg_d, agg_p);

    // 5) fused node updates (drug rows then prot rows of out)
    node_update_kernel<<<NU_BD + NU_BP, 256, 0, stream>>>(
        x_drug, x_prot, agg_d, agg_p,
        Wdrug, b_drug, g_drug, be_drug,
        Wprot, b_prot, g_prot, be_prot, out);
}

// Round 13
// 395.236 us; speedup vs baseline: 1.2929x; 1.0135x over previous
//
#include <hip/hip_runtime.h>

#define D 128
#define ND 100000
#define NP 50000
#define NE_DD 800000
#define NE_DP 600000
#define NE_PD 600000
#define NE_TOT 2000000

#define NTOT 250000      /* concatenated dst space: [dd:100k][pd:100k][dp:50k] */
#define NBC 490          /* coarse buckets, 512 nodes each (490*512 = 250880) */
#define NC 250880
#define CHUNKA 4096      /* edges per binning block (44KB LDS -> 3 blocks/CU) */
#define NBLKA 489        /* ceil(2M/4096) */
#define CHUNKIT 16       /* CHUNKA/256 */
#define SEGCAP 8192      /* max edges per coarse bucket (expected max ~6.6k) */

/* transform: drug waves do 32 rows (2 outputs), prot waves 64 rows */
#define TF_BD 782        /* ceil(100000/128) */
#define TF_BP 196        /* ceil(50000/256) */
/* node_update: every wave does 64 rows (M_rep=4) */
#define NU_BD 391        /* ceil(100000/256) */
#define NU_BP 196        /* ceil(50000/256) */

typedef __bf16 bf16;
typedef __attribute__((ext_vector_type(8))) __bf16 bf16x8;
typedef __attribute__((ext_vector_type(2))) __bf16 bf16x2;
typedef __attribute__((ext_vector_type(4))) float f32x4;
typedef __attribute__((ext_vector_type(2))) float f32x2;

// ---------------- workspace layout (byte offsets, 16B-aligned) -------------
// y_* arrays are fp8-e4m3 (half the bf16 footprint); offsets unchanged.
#define OFF_WDD   0UL
#define OFF_WDP   32768UL
#define OFF_WPD   65536UL
#define OFF_WDRUG 98304UL
#define OFF_WPROT 163840UL
#define OFF_YDD   229376UL                      /* 100k x 128 fp8 */
#define OFF_YDP   (OFF_YDD + 25600000UL)        /* 100k x 128 fp8 */
#define OFF_YPD   (OFF_YDP + 25600000UL)        /* 50k x 128 fp8 */
#define OFF_AGGD  (OFF_YPD + 12800000UL)        /* 100k x 128 bf16 */
#define OFF_AGGP  (OFF_AGGD + 25600000UL)       /* 50k x 128 bf16 */
#define OFF_BCNT  (OFF_AGGP + 12800000UL)       /* NBC ints (zeroed in prep) */
#define OFF_GCUR  (OFF_BCNT + 2048UL)           /* NBC ints */
#define OFF_CBASE (OFF_GCUR + 2048UL)           /* NBC+1 ints */
#define OFF_RP    (OFF_CBASE + 2048UL)          /* NC ints (row ptrs) */
#define OFF_PAIRS (OFF_RP + 1003520UL)          /* 2M u32 packed (ldst<<17|src) */
#define OFF_POOL  (OFF_PAIRS + 16000000UL)      /* 2M ints (node-grouped src) */

// ---------------- fp8 e4m3 encode (values >= 0 only; relu outputs) ---------
__device__ __forceinline__ unsigned enc1(float f)
{
    unsigned t = __float_as_uint(f * 0x1p-120f);
    t = (t + 0x80000u) >> 20;
    return t > 0x7Eu ? 0x7Eu : t;
}
__device__ __forceinline__ unsigned enc4(float a, float b, float c, float d)
{
    return enc1(a) | (enc1(b) << 8) | (enc1(c) << 16) | (enc1(d) << 24);
}

// ---------------- prep: weights->bf16  +  zero bcnt ------------------------
// W_drug / W_prot get their K in [128,256) columns permuted so that the agg
// half of the GEMM K-dim matches the permuted y/agg layout (position p holds
// original column (p%8)*16 + p/8).
__global__ __launch_bounds__(256) void prep_kernel(
    const float* __restrict__ w0, const float* __restrict__ w1,
    const float* __restrict__ w2, const float* __restrict__ w3,
    const float* __restrict__ w4,
    bf16* __restrict__ o0, bf16* __restrict__ o1, bf16* __restrict__ o2,
    bf16* __restrict__ o3, bf16* __restrict__ o4,
    int* __restrict__ bcnt)
{
    int m = blockIdx.y;
    int i = blockIdx.x * 256 + threadIdx.x;
    if (m == 5) {
        if (i < NBC) bcnt[i] = 0;
        return;
    }
    const float* src; bf16* dst; int n; bool perm;
    switch (m) {
        case 0: src = w0; dst = o0; n = D * D; perm = false; break;
        case 1: src = w1; dst = o1; n = D * D; perm = false; break;
        case 2: src = w2; dst = o2; n = D * D; perm = false; break;
        case 3: src = w3; dst = o3; n = D * 2 * D; perm = true; break;
        default: src = w4; dst = o4; n = D * 2 * D; perm = true; break;
    }
    if (i < n) {
        int si = i;
        if (perm) {
            int col = i & 255;
            if (col >= 128) {
                int p = col - 128;
                si = (i & ~255) | (128 + (p & 7) * 16 + (p >> 3));
            }
        }
        dst[i] = (bf16)src[si];
    }
}

// ---------------- per-node transforms: y = relu(x @ W^T), fp8 out ----------
__device__ __forceinline__ bf16x8 load_a_f32(const float* __restrict__ xr)
{
    float4 f0 = *(const float4*)xr;
    float4 f1 = *(const float4*)(xr + 4);
    bf16x8 a;
    a[0] = (bf16)f0.x; a[1] = (bf16)f0.y; a[2] = (bf16)f0.z; a[3] = (bf16)f0.w;
    a[4] = (bf16)f1.x; a[5] = (bf16)f1.y; a[6] = (bf16)f1.z; a[7] = (bf16)f1.w;
    return a;
}

__device__ __forceinline__ void transform_drug(
    const float* __restrict__ x, const bf16* __restrict__ W1,
    const bf16* __restrict__ W2, unsigned char* __restrict__ y1,
    unsigned char* __restrict__ y2, int blk)
{
    int lane = threadIdx.x & 63;
    int wave = threadIdx.x >> 6;
    int q = lane >> 4, c = lane & 15;
    int mb = blk * 128 + wave * 32;         /* 2 M-tiles per wave, 2 outputs */

    f32x4 acc1[2][8], acc2[2][8];
#pragma unroll
    for (int mt = 0; mt < 2; mt++)
#pragma unroll
        for (int nt = 0; nt < 8; nt++) { acc1[mt][nt] = 0; acc2[mt][nt] = 0; }

#pragma unroll
    for (int kb = 0; kb < 4; kb++) {
        int k = kb * 32 + q * 8;
        bf16x8 a[2];
#pragma unroll
        for (int mt = 0; mt < 2; mt++) {
            int row = min(mb + mt * 16 + c, ND - 1);
            a[mt] = load_a_f32(x + (long)row * D + k);
        }
#pragma unroll
        for (int nt = 0; nt < 8; nt++) {
            bf16x8 b1 = *(const bf16x8*)(W1 + (nt * 16 + c) * D + k);
            bf16x8 b2 = *(const bf16x8*)(W2 + (nt * 16 + c) * D + k);
#pragma unroll
            for (int mt = 0; mt < 2; mt++) {
                acc1[mt][nt] = __builtin_amdgcn_mfma_f32_16x16x32_bf16(a[mt], b1, acc1[mt][nt], 0, 0, 0);
                acc2[mt][nt] = __builtin_amdgcn_mfma_f32_16x16x32_bf16(a[mt], b2, acc2[mt][nt], 0, 0, 0);
            }
        }
    }
#pragma unroll
    for (int mt = 0; mt < 2; mt++)
#pragma unroll
        for (int r = 0; r < 4; r++) {
            int row = mb + mt * 16 + q * 4 + r;
            if (row < ND) {
                float v1[8], v2[8];
#pragma unroll
                for (int nt = 0; nt < 8; nt++) {
                    v1[nt] = fmaxf(acc1[mt][nt][r], 0.f);
                    v2[nt] = fmaxf(acc2[mt][nt][r], 0.f);
                }
                uint2 p1, p2;
                p1.x = enc4(v1[0], v1[1], v1[2], v1[3]);
                p1.y = enc4(v1[4], v1[5], v1[6], v1[7]);
                p2.x = enc4(v2[0], v2[1], v2[2], v2[3]);
                p2.y = enc4(v2[4], v2[5], v2[6], v2[7]);
                *(uint2*)(y1 + (long)row * D + c * 8) = p1;
                *(uint2*)(y2 + (long)row * D + c * 8) = p2;
            }
        }
}

__device__ __forceinline__ void transform_prot(
    const float* __restrict__ x, const bf16* __restrict__ W1,
    unsigned char* __restrict__ y1, int blk)
{
    int lane = threadIdx.x & 63;
    int wave = threadIdx.x >> 6;
    int q = lane >> 4, c = lane & 15;
    int mb = blk * 256 + wave * 64;         /* 4 M-tiles per wave, 1 output */

    f32x4 acc[4][8];
#pragma unroll
    for (int mt = 0; mt < 4; mt++)
#pragma unroll
        for (int nt = 0; nt < 8; nt++) acc[mt][nt] = 0;

#pragma unroll
    for (int kb = 0; kb < 4; kb++) {
        int k = kb * 32 + q * 8;
        bf16x8 a[4];
#pragma unroll
        for (int mt = 0; mt < 4; mt++) {
            int row = min(mb + mt * 16 + c, NP - 1);
            a[mt] = load_a_f32(x + (long)row * D + k);
        }
#pragma unroll
        for (int nt = 0; nt < 8; nt++) {
            bf16x8 b1 = *(const bf16x8*)(W1 + (nt * 16 + c) * D + k);
#pragma unroll
            for (int mt = 0; mt < 4; mt++)
                acc[mt][nt] = __builtin_amdgcn_mfma_f32_16x16x32_bf16(a[mt], b1, acc[mt][nt], 0, 0, 0);
        }
    }
#pragma unroll
    for (int mt = 0; mt < 4; mt++)
#pragma unroll
        for (int r = 0; r < 4; r++) {
            int row = mb + mt * 16 + q * 4 + r;
            if (row < NP) {
                float v[8];
#pragma unroll
                for (int nt = 0; nt < 8; nt++)
                    v[nt] = fmaxf(acc[mt][nt][r], 0.f);
                uint2 p1;
                p1.x = enc4(v[0], v[1], v[2], v[3]);
                p1.y = enc4(v[4], v[5], v[6], v[7]);
                *(uint2*)(y1 + (long)row * D + c * 8) = p1;
            }
        }
}

__global__ __launch_bounds__(256, 2) void transform_kernel(
    const float* __restrict__ x_drug, const float* __restrict__ x_prot,
    const bf16* __restrict__ Wdd, const bf16* __restrict__ Wdp,
    const bf16* __restrict__ Wpd,
    unsigned char* __restrict__ y_dd, unsigned char* __restrict__ y_dp,
    unsigned char* __restrict__ y_pd)
{
    int blk = blockIdx.x;
    if (blk < TF_BD)
        transform_drug(x_drug, Wdd, Wdp, y_dd, y_dp, blk);
    else
        transform_prot(x_prot, Wpd, y_pd, blk - TF_BD);
}

// ---------------- coarse histogram (LDS-staged) ----------------------------
__global__ __launch_bounds__(256) void hist_kernel(
    const int* __restrict__ dd_dst, const int* __restrict__ pd_dst,
    const int* __restrict__ dp_dst, int* __restrict__ bcnt)
{
    __shared__ int h[NBC];
    for (int i = threadIdx.x; i < NBC; i += 256) h[i] = 0;
    __syncthreads();
    int base = blockIdx.x * CHUNKA;
    for (int it = 0; it < CHUNKIT; it++) {
        int e = base + it * 256 + threadIdx.x;
        if (e < NE_TOT) {
            int didx;
            if (e < NE_DD) didx = dd_dst[e];
            else if (e < NE_DD + NE_PD) didx = ND + pd_dst[e - NE_DD];
            else didx = 2 * ND + dp_dst[e - NE_DD - NE_PD];
            atomicAdd(&h[didx >> 9], 1);
        }
    }
    __syncthreads();
    for (int i = threadIdx.x; i < NBC; i += 256)
        if (h[i]) atomicAdd(&bcnt[i], h[i]);
}

// ---------------- exclusive scan over 490 bucket counts (1 block) ----------
__global__ __launch_bounds__(256) void scan_kernel(
    const int* __restrict__ bcnt, int* __restrict__ cbase, int* __restrict__ gcur)
{
    __shared__ int ps[256];
    int t = threadIdx.x;
    int i0 = 2 * t, i1 = 2 * t + 1;
    int c0 = (i0 < NBC) ? bcnt[i0] : 0;
    int c1 = (i1 < NBC) ? bcnt[i1] : 0;
    ps[t] = c0 + c1;
    __syncthreads();
#pragma unroll
    for (int off = 1; off < 256; off <<= 1) {
        int add = (t >= off) ? ps[t - off] : 0;
        __syncthreads();
        ps[t] += add;
        __syncthreads();
    }
    int excl = ps[t] - (c0 + c1);
    if (i0 <= NBC) cbase[i0] = excl;            /* i0==NBC writes the sentinel */
    if (i0 < NBC) gcur[i0] = excl;
    if (i1 < NBC) { cbase[i1] = excl + c0; gcur[i1] = excl + c0; }
}

// ---------------- pass A: coarse binning, packed u32 output ----------------
// pairs packed as (local_dst<<17 | src): src < 2^17, local_dst < 512.
__global__ __launch_bounds__(256) void binA_kernel(
    const int* __restrict__ dd_src, const int* __restrict__ dd_dst,
    const int* __restrict__ pd_src, const int* __restrict__ pd_dst,
    const int* __restrict__ dp_src, const int* __restrict__ dp_dst,
    int* __restrict__ gcur, unsigned* __restrict__ pairs)
{
    __shared__ int h[NBC];
    __shared__ int gb[NBC];
    __shared__ int2 pr[CHUNKA];
    __shared__ unsigned short rk[CHUNKA];
    for (int i = threadIdx.x; i < NBC; i += 256) h[i] = 0;
    __syncthreads();
    int base = blockIdx.x * CHUNKA;
    for (int it = 0; it < CHUNKIT; it++) {
        int idx = it * 256 + threadIdx.x;
        int e = base + idx;
        int didx = -1, sv = 0;
        if (e < NE_TOT) {
            if (e < NE_DD) { didx = dd_dst[e]; sv = dd_src[e]; }
            else if (e < NE_DD + NE_PD) { int u = e - NE_DD; didx = ND + pd_dst[u]; sv = pd_src[u]; }
            else { int u = e - NE_DD - NE_PD; didx = 2 * ND + dp_dst[u]; sv = dp_src[u]; }
            rk[idx] = (unsigned short)atomicAdd(&h[didx >> 9], 1);
        }
        pr[idx] = make_int2(didx, sv);
    }
    __syncthreads();
    for (int b = threadIdx.x; b < NBC; b += 256) {
        int c = h[b];
        gb[b] = c ? atomicAdd(&gcur[b], c) : 0;
    }
    __syncthreads();
    for (int it = 0; it < CHUNKIT; it++) {
        int idx = it * 256 + threadIdx.x;
        int2 p = pr[idx];
        if (p.x >= 0)
            pairs[gb[p.x >> 9] + rk[idx]] =
                ((unsigned)(p.x & 511) << 17) | (unsigned)p.y;
    }
}

// ---------------- pass B: per-bucket LDS counting sort -> pool + rp --------
__global__ __launch_bounds__(256) void sortB_kernel(
    const int* __restrict__ cbase, const unsigned* __restrict__ pairs,
    int* __restrict__ pool, int* __restrict__ rp)
{
    __shared__ int h[512];
    __shared__ int excl[512];
    __shared__ int ps[256];
    __shared__ unsigned short rk[SEGCAP];
    __shared__ int outl[SEGCAP];

    int b = blockIdx.x;
    int s0 = cbase[b], s1 = cbase[b + 1];
    int n = s1 - s0;
    if (n > SEGCAP) n = SEGCAP;   /* safety clamp; expected max ~6.6k */
    int t = threadIdx.x;
    h[t] = 0; h[t + 256] = 0;
    __syncthreads();

    for (int i = t; i < n; i += 256) {
        unsigned p = pairs[s0 + i];
        rk[i] = (unsigned short)atomicAdd(&h[p >> 17], 1);
    }
    __syncthreads();

    // exclusive scan over h[0..511] (2 elems per thread)
    int c0 = h[2 * t], c1 = h[2 * t + 1];
    ps[t] = c0 + c1;
    __syncthreads();
#pragma unroll
    for (int off = 1; off < 256; off <<= 1) {
        int add = (t >= off) ? ps[t - off] : 0;
        __syncthreads();
        ps[t] += add;
        __syncthreads();
    }
    int pe = ps[t] - (c0 + c1);
    excl[2 * t] = pe;
    excl[2 * t + 1] = pe + c0;
    __syncthreads();

    // row pointers for this bucket's 512 node slots
    int nb = b * 512;
    rp[nb + 2 * t] = s0 + excl[2 * t];
    rp[nb + 2 * t + 1] = s0 + excl[2 * t + 1];

    // LDS scatter (pairs re-read), then coalesced copy out
    for (int i = t; i < n; i += 256) {
        unsigned p = pairs[s0 + i];
        outl[excl[p >> 17] + rk[i]] = (int)(p & 0x1FFFFu);
    }
    __syncthreads();
    for (int i = t; i < n; i += 256)
        pool[s0 + i] = outl[i];
}

// ---------------- gather: one node per wave, 64 lanes x 2B fp8 -------------
// fp8 rows are 128B = 1 cache line per edge.  Decode: f32 = as_float(em<<20)
// * 2^120 (exact for e4m3 normals).  Drug nodes interleave dd/pd segments
// (4+4 loads in flight) to overlap the two serial latency chains.
__device__ __forceinline__ void accw(unsigned short w, f32x2* acc)
{
    float lo = __uint_as_float((unsigned)(w & 0xFFu) << 20);
    float hi = __uint_as_float((unsigned)(w >> 8) << 20);
    acc->x = fmaf(lo, 0x1p120f, acc->x);
    acc->y = fmaf(hi, 0x1p120f, acc->y);
}

__device__ __forceinline__ void acc_seg(
    const int* __restrict__ pool, int s, int e,
    const unsigned short* __restrict__ y, int lane, f32x2* acc)
{
    int j = s;
    for (; j + 8 <= e; j += 8) {
        unsigned short u[8];
#pragma unroll
        for (int t = 0; t < 8; t++)
            u[t] = y[(long)pool[j + t] * 64 + lane];
#pragma unroll
        for (int t = 0; t < 8; t++) accw(u[t], acc);
    }
    if (j + 4 <= e) {
        unsigned short u[4];
#pragma unroll
        for (int t = 0; t < 4; t++)
            u[t] = y[(long)pool[j + t] * 64 + lane];
#pragma unroll
        for (int t = 0; t < 4; t++) accw(u[t], acc);
        j += 4;
    }
    if (j + 2 <= e) {
        unsigned short u0 = y[(long)pool[j] * 64 + lane];
        unsigned short u1 = y[(long)pool[j + 1] * 64 + lane];
        accw(u0, acc); accw(u1, acc);
        j += 2;
    }
    if (j < e)
        accw(y[(long)pool[j] * 64 + lane], acc);
}

__global__ __launch_bounds__(256) void gather_kernel(
    const int* __restrict__ rp, const int* __restrict__ pool,
    const unsigned short* __restrict__ y_dd,
    const unsigned short* __restrict__ y_pd,
    const unsigned short* __restrict__ y_dp,
    bf16* __restrict__ agg_d, bf16* __restrict__ agg_p)
{
    int wid = blockIdx.x * 4 + (threadIdx.x >> 6);
    int lane = threadIdx.x & 63;

    if (wid < ND) {
        int g = wid;
        int s1 = rp[g], e1 = rp[g + 1];
        int s2 = rp[ND + g], e2 = rp[ND + g + 1];
        f32x2 a; a.x = 0.f; a.y = 0.f;
        f32x2 b; b.x = 0.f; b.y = 0.f;
        int j1 = s1, j2 = s2;
        // interleaved 4+4: both segments' loads in flight together
        while (j1 + 4 <= e1 && j2 + 4 <= e2) {
            unsigned short ua[4], ub[4];
#pragma unroll
            for (int t = 0; t < 4; t++)
                ua[t] = y_dd[(long)pool[j1 + t] * 64 + lane];
#pragma unroll
            for (int t = 0; t < 4; t++)
                ub[t] = y_pd[(long)pool[j2 + t] * 64 + lane];
#pragma unroll
            for (int t = 0; t < 4; t++) accw(ua[t], &a);
#pragma unroll
            for (int t = 0; t < 4; t++) accw(ub[t], &b);
            j1 += 4; j2 += 4;
        }
        acc_seg(pool, j1, e1, y_dd, lane, &a);
        acc_seg(pool, j2, e2, y_pd, lane, &b);
        float i1 = 0.5f / (float)max(e1 - s1, 1);
        float i2 = 0.5f / (float)max(e2 - s2, 1);
        f32x2 r = a * i1 + b * i2;
        bf16x2 o; o[0] = (bf16)r.x; o[1] = (bf16)r.y;
        *(bf16x2*)(agg_d + (long)g * D + lane * 2) = o;
    } else if (wid < ND + NP) {
        int p = wid - ND;
        int s1 = rp[2 * ND + p], e1 = rp[2 * ND + p + 1];
        f32x2 a; a.x = 0.f; a.y = 0.f;
        acc_seg(pool, s1, e1, y_dp, lane, &a);
        float i1 = 1.0f / (float)max(e1 - s1, 1);
        f32x2 r = a * i1;
        bf16x2 o; o[0] = (bf16)r.x; o[1] = (bf16)r.y;
        *(bf16x2*)(agg_p + (long)p * D + lane * 2) = o;
    }
}

// ---------------- fused node update: GEMM(K=256) + bias+relu+residual+LN ---
__device__ __forceinline__ void node_update_body(
    const float* __restrict__ x, const bf16* __restrict__ agg,
    const bf16* __restrict__ W, const float* __restrict__ b,
    const float* __restrict__ g, const float* __restrict__ be,
    float* __restrict__ out, int M, int blk)
{
    int lane = threadIdx.x & 63;
    int wave = threadIdx.x >> 6;
    int q = lane >> 4, c = lane & 15;
    int mb = blk * 256 + wave * 64;

    f32x4 acc[4][8];
#pragma unroll
    for (int mt = 0; mt < 4; mt++)
#pragma unroll
        for (int nt = 0; nt < 8; nt++) acc[mt][nt] = 0;

#pragma unroll
    for (int kb = 0; kb < 8; kb++) {
        bf16x8 a[4];
#pragma unroll
        for (int mt = 0; mt < 4; mt++) {
            int row = min(mb + mt * 16 + c, M - 1);
            if (kb < 4)
                a[mt] = load_a_f32(x + (long)row * D + kb * 32 + q * 8);
            else
                a[mt] = *(const bf16x8*)(agg + (long)row * D + (kb - 4) * 32 + q * 8);
        }
#pragma unroll
        for (int nt = 0; nt < 8; nt++) {
            bf16x8 bw = *(const bf16x8*)(W + (nt * 16 + c) * (2 * D) + kb * 32 + q * 8);
#pragma unroll
            for (int mt = 0; mt < 4; mt++)
                acc[mt][nt] = __builtin_amdgcn_mfma_f32_16x16x32_bf16(a[mt], bw, acc[mt][nt], 0, 0, 0);
        }
    }

    float bv[8], gv[8], bev[8];
#pragma unroll
    for (int nt = 0; nt < 8; nt++) {
        int col = nt * 16 + c;
        bv[nt] = b[col]; gv[nt] = g[col]; bev[nt] = be[col];
    }
#pragma unroll
    for (int mt = 0; mt < 4; mt++)
#pragma unroll
        for (int r = 0; r < 4; r++) {
            int row = mb + mt * 16 + q * 4 + r;
            int rowc = min(row, M - 1);
            const float* xr = x + (long)rowc * D + c;
            float v[8];
            float sum = 0.f, sq = 0.f;
#pragma unroll
            for (int nt = 0; nt < 8; nt++) {
                float h = fmaxf(acc[mt][nt][r] + bv[nt], 0.f);
                float t = h + xr[nt * 16];
                v[nt] = t; sum += t; sq += t * t;
            }
#pragma unroll
            for (int m = 1; m < 16; m <<= 1) {
                sum += __shfl_xor(sum, m, 64);
                sq  += __shfl_xor(sq,  m, 64);
            }
            float mu   = sum * (1.f / 128.f);
            float var  = sq  * (1.f / 128.f) - mu * mu;
            float rstd = rsqrtf(var + 1e-5f);
            if (row < M) {
                float* op = out + (long)row * D + c;
#pragma unroll
                for (int nt = 0; nt < 8; nt++)
                    op[nt * 16] = (v[nt] - mu) * rstd * gv[nt] + bev[nt];
            }
        }
}

__global__ __launch_bounds__(256, 2) void node_update_kernel(
    const float* __restrict__ x_drug, const float* __restrict__ x_prot,
    const bf16* __restrict__ agg_d, const bf16* __restrict__ agg_p,
    const bf16* __restrict__ Wdrug, const float* __restrict__ b_drug,
    const float* __restrict__ g_drug, const float* __restrict__ be_drug,
    const bf16* __restrict__ Wprot, const float* __restrict__ b_prot,
    const float* __restrict__ g_prot, const float* __restrict__ be_prot,
    float* __restrict__ out)
{
    int blk = blockIdx.x;
    if (blk < NU_BD)
        node_update_body(x_drug, agg_d, Wdrug, b_drug, g_drug, be_drug,
                         out, ND, blk);
    else
        node_update_body(x_prot, agg_p, Wprot, b_prot, g_prot, be_prot,
                         out + (long)ND * D, NP, blk - NU_BD);
}

extern "C" void kernel_launch(void* const* d_in, const int* in_sizes, int n_in,
                              void* d_out, int out_size, void* d_ws, size_t ws_size,
                              hipStream_t stream)
{
    const float* x_drug  = (const float*)d_in[0];
    const float* x_prot  = (const float*)d_in[1];
    const float* Wagg_dd = (const float*)d_in[2];
    const float* Wagg_dp = (const float*)d_in[3];
    const float* Wagg_pd = (const float*)d_in[4];
    const float* W_drug  = (const float*)d_in[5];
    const float* b_drug  = (const float*)d_in[6];
    const float* W_prot  = (const float*)d_in[7];
    const float* b_prot  = (const float*)d_in[8];
    const float* g_drug  = (const float*)d_in[9];
    const float* be_drug = (const float*)d_in[10];
    const float* g_prot  = (const float*)d_in[11];
    const float* be_prot = (const float*)d_in[12];
    const int* dd_src = (const int*)d_in[13];
    const int* dd_dst = (const int*)d_in[14];
    const int* dp_src = (const int*)d_in[15];
    const int* dp_dst = (const int*)d_in[16];
    const int* pd_src = (const int*)d_in[17];
    const int* pd_dst = (const int*)d_in[18];

    char* ws = (char*)d_ws;
    bf16* Wdd   = (bf16*)(ws + OFF_WDD);
    bf16* Wdp   = (bf16*)(ws + OFF_WDP);
    bf16* Wpd   = (bf16*)(ws + OFF_WPD);
    bf16* Wdrug = (bf16*)(ws + OFF_WDRUG);
    bf16* Wprot = (bf16*)(ws + OFF_WPROT);
    unsigned char* y_dd = (unsigned char*)(ws + OFF_YDD);
    unsigned char* y_dp = (unsigned char*)(ws + OFF_YDP);
    unsigned char* y_pd = (unsigned char*)(ws + OFF_YPD);
    bf16* agg_d = (bf16*)(ws + OFF_AGGD);
    bf16* agg_p = (bf16*)(ws + OFF_AGGP);
    int* bcnt   = (int*)(ws + OFF_BCNT);
    int* gcur   = (int*)(ws + OFF_GCUR);
    int* cbase  = (int*)(ws + OFF_CBASE);
    int* rp     = (int*)(ws + OFF_RP);
    unsigned* pairs = (unsigned*)(ws + OFF_PAIRS);
    int* pool   = (int*)(ws + OFF_POOL);
    float* out  = (float*)d_out;

    // 1) weights->bf16 (+K-permutation for node-update W) + zero histogram
    prep_kernel<<<dim3(128, 6), 256, 0, stream>>>(
        Wagg_dd, Wagg_dp, Wagg_pd, W_drug, W_prot,
        Wdd, Wdp, Wpd, Wdrug, Wprot, bcnt);

    // 2) per-node transforms (drug: dd+dp, prot: pd) -> fp8 y
    transform_kernel<<<TF_BD + TF_BP, 256, 0, stream>>>(
        x_drug, x_prot, Wdd, Wdp, Wpd, y_dd, y_dp, y_pd);

    // 3) two-level counting sort of edges by destination (packed u32 pairs)
    hist_kernel<<<NBLKA, 256, 0, stream>>>(dd_dst, pd_dst, dp_dst, bcnt);
    scan_kernel<<<1, 256, 0, stream>>>(bcnt, cbase, gcur);
    binA_kernel<<<NBLKA, 256, 0, stream>>>(
        dd_src, dd_dst, pd_src, pd_dst, dp_src, dp_dst, gcur, pairs);
    sortB_kernel<<<NBC, 256, 0, stream>>>(cbase, pairs, pool, rp);

    // 4) gather + per-relation mean (one node per wave, fp8 rows = 1 line)
    gather_kernel<<<(ND + NP + 3) / 4, 256, 0, stream>>>(
        rp, pool, (const unsigned short*)y_dd, (const unsigned short*)y_pd,
        (const unsigned short*)y_dp, agg_d, agg_p);

    // 5) fused node updates (drug rows then prot rows of out)
    node_update_kernel<<<NU_BD + NU_BP, 256, 0, stream>>>(
        x_drug, x_prot, agg_d, agg_p,
        Wdrug, b_drug, g_drug, be_drug,
        Wprot, b_prot, g_prot, be_prot, out);
}

// Round 15
// 374.764 us; speedup vs baseline: 1.3636x; 1.0546x over previous
//
#include <hip/hip_runtime.h>

#define D 128
#define ND 100000
#define NP 50000
#define NE_DD 800000
#define NE_DP 600000
#define NE_PD 600000
#define NE_TOT 2000000

#define NTOT 250000      /* concatenated dst space: [dd:100k][pd:100k][dp:50k] */
#define NBC 490          /* coarse buckets, 512 nodes each (490*512 = 250880) */
#define CHUNKA 4096      /* edges per binning block (44KB LDS -> 3 blocks/CU) */
#define NBLKA 489        /* ceil(2M/4096) */
#define CHUNKIT 16       /* CHUNKA/256 */
#define SEGCAP 8192      /* static slots per coarse bucket (max seen ~6.6k) */
#define RPS 513          /* rp stride per bucket: 512 starts + end sentinel */

/* transform: drug waves do 32 rows (2 outputs), prot waves 64 rows */
#define TF_BD 782        /* ceil(100000/128) */
#define TF_BP 196        /* ceil(50000/256) */
/* node_update: every wave does 64 rows (M_rep=4) */
#define NU_BD 391        /* ceil(100000/256) */
#define NU_BP 196        /* ceil(50000/256) */

typedef __bf16 bf16;
typedef __attribute__((ext_vector_type(8))) __bf16 bf16x8;
typedef __attribute__((ext_vector_type(2))) __bf16 bf16x2;
typedef __attribute__((ext_vector_type(4))) float f32x4;
typedef __attribute__((ext_vector_type(2))) float f32x2;

// ---------------- workspace layout (byte offsets, 16B-aligned) -------------
// Repacked for fp8 y.  Static bucket regions: pairs/pool strided at b*SEGCAP,
// rp strided at b*RPS.  No hist/scan/cbase needed.  Total ~103.7 MB.
#define OFF_WDD   0UL
#define OFF_WDP   32768UL
#define OFF_WPD   65536UL
#define OFF_WDRUG 98304UL
#define OFF_WPROT 163840UL
#define OFF_YDD   229376UL                      /* 100k x 128 fp8 */
#define OFF_YDP   (OFF_YDD + 12800000UL)        /* 100k x 128 fp8 */
#define OFF_YPD   (OFF_YDP + 12800000UL)        /* 50k x 128 fp8 */
#define OFF_AGGD  (OFF_YPD + 6400000UL)         /* 100k x 128 bf16 */
#define OFF_AGGP  (OFF_AGGD + 25600000UL)       /* 50k x 128 bf16 */
#define OFF_GCUR  (OFF_AGGP + 12800000UL)       /* NBC ints (zeroed in prep) */
#define OFF_RP    (OFF_GCUR + 2048UL)           /* NBC*RPS ints */
#define OFF_PAIRS (OFF_RP + 1005568UL)          /* NBC*SEGCAP u32 (static) */
#define OFF_POOL  (OFF_PAIRS + 16056320UL)      /* NBC*SEGCAP ints (static) */

// ---------------- fp8 e4m3 encode (values >= 0 only; relu outputs) ---------
__device__ __forceinline__ unsigned enc1(float f)
{
    unsigned t = __float_as_uint(f * 0x1p-120f);
    t = (t + 0x80000u) >> 20;
    return t > 0x7Eu ? 0x7Eu : t;
}
__device__ __forceinline__ unsigned enc4(float a, float b, float c, float d)
{
    return enc1(a) | (enc1(b) << 8) | (enc1(c) << 16) | (enc1(d) << 24);
}

// ---------------- prep: weights->bf16  +  zero gcur ------------------------
// W_drug / W_prot get their K in [128,256) columns permuted so that the agg
// half of the GEMM K-dim matches the permuted y/agg layout.
__global__ __launch_bounds__(256) void prep_kernel(
    const float* __restrict__ w0, const float* __restrict__ w1,
    const float* __restrict__ w2, const float* __restrict__ w3,
    const float* __restrict__ w4,
    bf16* __restrict__ o0, bf16* __restrict__ o1, bf16* __restrict__ o2,
    bf16* __restrict__ o3, bf16* __restrict__ o4,
    int* __restrict__ gcur)
{
    int m = blockIdx.y;
    int i = blockIdx.x * 256 + threadIdx.x;
    if (m == 5) {
        if (i < NBC) gcur[i] = 0;
        return;
    }
    const float* src; bf16* dst; int n; bool perm;
    switch (m) {
        case 0: src = w0; dst = o0; n = D * D; perm = false; break;
        case 1: src = w1; dst = o1; n = D * D; perm = false; break;
        case 2: src = w2; dst = o2; n = D * D; perm = false; break;
        case 3: src = w3; dst = o3; n = D * 2 * D; perm = true; break;
        default: src = w4; dst = o4; n = D * 2 * D; perm = true; break;
    }
    if (i < n) {
        int si = i;
        if (perm) {
            int col = i & 255;
            if (col >= 128) {
                int p = col - 128;
                si = (i & ~255) | (128 + (p & 7) * 16 + (p >> 3));
            }
        }
        dst[i] = (bf16)src[si];
    }
}

// ---------------- per-node transforms: y = relu(x @ W^T), fp8 out ----------
__device__ __forceinline__ bf16x8 load_a_f32(const float* __restrict__ xr)
{
    float4 f0 = *(const float4*)xr;
    float4 f1 = *(const float4*)(xr + 4);
    bf16x8 a;
    a[0] = (bf16)f0.x; a[1] = (bf16)f0.y; a[2] = (bf16)f0.z; a[3] = (bf16)f0.w;
    a[4] = (bf16)f1.x; a[5] = (bf16)f1.y; a[6] = (bf16)f1.z; a[7] = (bf16)f1.w;
    return a;
}

__device__ __forceinline__ void transform_drug(
    const float* __restrict__ x, const bf16* __restrict__ W1,
    const bf16* __restrict__ W2, unsigned char* __restrict__ y1,
    unsigned char* __restrict__ y2, int blk)
{
    int lane = threadIdx.x & 63;
    int wave = threadIdx.x >> 6;
    int q = lane >> 4, c = lane & 15;
    int mb = blk * 128 + wave * 32;         /* 2 M-tiles per wave, 2 outputs */

    f32x4 acc1[2][8], acc2[2][8];
#pragma unroll
    for (int mt = 0; mt < 2; mt++)
#pragma unroll
        for (int nt = 0; nt < 8; nt++) { acc1[mt][nt] = 0; acc2[mt][nt] = 0; }

#pragma unroll
    for (int kb = 0; kb < 4; kb++) {
        int k = kb * 32 + q * 8;
        bf16x8 a[2];
#pragma unroll
        for (int mt = 0; mt < 2; mt++) {
            int row = min(mb + mt * 16 + c, ND - 1);
            a[mt] = load_a_f32(x + (long)row * D + k);
        }
#pragma unroll
        for (int nt = 0; nt < 8; nt++) {
            bf16x8 b1 = *(const bf16x8*)(W1 + (nt * 16 + c) * D + k);
            bf16x8 b2 = *(const bf16x8*)(W2 + (nt * 16 + c) * D + k);
#pragma unroll
            for (int mt = 0; mt < 2; mt++) {
                acc1[mt][nt] = __builtin_amdgcn_mfma_f32_16x16x32_bf16(a[mt], b1, acc1[mt][nt], 0, 0, 0);
                acc2[mt][nt] = __builtin_amdgcn_mfma_f32_16x16x32_bf16(a[mt], b2, acc2[mt][nt], 0, 0, 0);
            }
        }
    }
#pragma unroll
    for (int mt = 0; mt < 2; mt++)
#pragma unroll
        for (int r = 0; r < 4; r++) {
            int row = mb + mt * 16 + q * 4 + r;
            if (row < ND) {
                float v1[8], v2[8];
#pragma unroll
                for (int nt = 0; nt < 8; nt++) {
                    v1[nt] = fmaxf(acc1[mt][nt][r], 0.f);
                    v2[nt] = fmaxf(acc2[mt][nt][r], 0.f);
                }
                uint2 p1, p2;
                p1.x = enc4(v1[0], v1[1], v1[2], v1[3]);
                p1.y = enc4(v1[4], v1[5], v1[6], v1[7]);
                p2.x = enc4(v2[0], v2[1], v2[2], v2[3]);
                p2.y = enc4(v2[4], v2[5], v2[6], v2[7]);
                *(uint2*)(y1 + (long)row * D + c * 8) = p1;
                *(uint2*)(y2 + (long)row * D + c * 8) = p2;
            }
        }
}

__device__ __forceinline__ void transform_prot(
    const float* __restrict__ x, const bf16* __restrict__ W1,
    unsigned char* __restrict__ y1, int blk)
{
    int lane = threadIdx.x & 63;
    int wave = threadIdx.x >> 6;
    int q = lane >> 4, c = lane & 15;
    int mb = blk * 256 + wave * 64;         /* 4 M-tiles per wave, 1 output */

    f32x4 acc[4][8];
#pragma unroll
    for (int mt = 0; mt < 4; mt++)
#pragma unroll
        for (int nt = 0; nt < 8; nt++) acc[mt][nt] = 0;

#pragma unroll
    for (int kb = 0; kb < 4; kb++) {
        int k = kb * 32 + q * 8;
        bf16x8 a[4];
#pragma unroll
        for (int mt = 0; mt < 4; mt++) {
            int row = min(mb + mt * 16 + c, NP - 1);
            a[mt] = load_a_f32(x + (long)row * D + k);
        }
#pragma unroll
        for (int nt = 0; nt < 8; nt++) {
            bf16x8 b1 = *(const bf16x8*)(W1 + (nt * 16 + c) * D + k);
#pragma unroll
            for (int mt = 0; mt < 4; mt++)
                acc[mt][nt] = __builtin_amdgcn_mfma_f32_16x16x32_bf16(a[mt], b1, acc[mt][nt], 0, 0, 0);
        }
    }
#pragma unroll
    for (int mt = 0; mt < 4; mt++)
#pragma unroll
        for (int r = 0; r < 4; r++) {
            int row = mb + mt * 16 + q * 4 + r;
            if (row < NP) {
                float v[8];
#pragma unroll
                for (int nt = 0; nt < 8; nt++)
                    v[nt] = fmaxf(acc[mt][nt][r], 0.f);
                uint2 p1;
                p1.x = enc4(v[0], v[1], v[2], v[3]);
                p1.y = enc4(v[4], v[5], v[6], v[7]);
                *(uint2*)(y1 + (long)row * D + c * 8) = p1;
            }
        }
}

__global__ __launch_bounds__(256, 2) void transform_kernel(
    const float* __restrict__ x_drug, const float* __restrict__ x_prot,
    const bf16* __restrict__ Wdd, const bf16* __restrict__ Wdp,
    const bf16* __restrict__ Wpd,
    unsigned char* __restrict__ y_dd, unsigned char* __restrict__ y_dp,
    unsigned char* __restrict__ y_pd)
{
    int blk = blockIdx.x;
    if (blk < TF_BD)
        transform_drug(x_drug, Wdd, Wdp, y_dd, y_dp, blk);
    else
        transform_prot(x_prot, Wpd, y_pd, blk - TF_BD);
}

// ---------------- binning: LDS-staged counts -> static bucket regions ------
// No histogram/scan pre-pass: gcur starts at 0 and each bucket's pairs live
// at the static region [b*SEGCAP, (b+1)*SEGCAP).  Packed u32 (ldst<<17|src).
__global__ __launch_bounds__(256) void binA_kernel(
    const int* __restrict__ dd_src, const int* __restrict__ dd_dst,
    const int* __restrict__ pd_src, const int* __restrict__ pd_dst,
    const int* __restrict__ dp_src, const int* __restrict__ dp_dst,
    int* __restrict__ gcur, unsigned* __restrict__ pairs)
{
    __shared__ int h[NBC];
    __shared__ int gb[NBC];
    __shared__ int2 pr[CHUNKA];
    __shared__ unsigned short rk[CHUNKA];
    for (int i = threadIdx.x; i < NBC; i += 256) h[i] = 0;
    __syncthreads();
    int base = blockIdx.x * CHUNKA;
    for (int it = 0; it < CHUNKIT; it++) {
        int idx = it * 256 + threadIdx.x;
        int e = base + idx;
        int didx = -1, sv = 0;
        if (e < NE_TOT) {
            if (e < NE_DD) { didx = dd_dst[e]; sv = dd_src[e]; }
            else if (e < NE_DD + NE_PD) { int u = e - NE_DD; didx = ND + pd_dst[u]; sv = pd_src[u]; }
            else { int u = e - NE_DD - NE_PD; didx = 2 * ND + dp_dst[u]; sv = dp_src[u]; }
            rk[idx] = (unsigned short)atomicAdd(&h[didx >> 9], 1);
        }
        pr[idx] = make_int2(didx, sv);
    }
    __syncthreads();
    for (int b = threadIdx.x; b < NBC; b += 256) {
        int c = h[b];
        gb[b] = c ? atomicAdd(&gcur[b], c) : 0;
    }
    __syncthreads();
    for (int it = 0; it < CHUNKIT; it++) {
        int idx = it * 256 + threadIdx.x;
        int2 p = pr[idx];
        if (p.x >= 0) {
            int b = p.x >> 9;
            int pos = gb[b] + rk[idx];
            if (pos < SEGCAP)   /* overflow guard; max observed ~6.6k */
                pairs[(long)b * SEGCAP + pos] =
                    ((unsigned)(p.x & 511) << 17) | (unsigned)p.y;
        }
    }
}

// ---------------- pass B: per-bucket LDS counting sort -> pool + rp --------
// rp strided RPS=513 per bucket: 512 node starts + end sentinel (s0+n).
__global__ __launch_bounds__(256) void sortB_kernel(
    const int* __restrict__ gcur, const unsigned* __restrict__ pairs,
    int* __restrict__ pool, int* __restrict__ rp)
{
    __shared__ int h[512];
    __shared__ int excl[512];
    __shared__ int ps[256];
    __shared__ unsigned short rk[SEGCAP];
    __shared__ int outl[SEGCAP];

    int b = blockIdx.x;
    int s0 = b * SEGCAP;
    int n = gcur[b];
    if (n > SEGCAP) n = SEGCAP;
    int t = threadIdx.x;
    h[t] = 0; h[t + 256] = 0;
    __syncthreads();

    for (int i = t; i < n; i += 256) {
        unsigned p = pairs[s0 + i];
        rk[i] = (unsigned short)atomicAdd(&h[p >> 17], 1);
    }
    __syncthreads();

    // exclusive scan over h[0..511] (2 elems per thread)
    int c0 = h[2 * t], c1 = h[2 * t + 1];
    ps[t] = c0 + c1;
    __syncthreads();
#pragma unroll
    for (int off = 1; off < 256; off <<= 1) {
        int add = (t >= off) ? ps[t - off] : 0;
        __syncthreads();
        ps[t] += add;
        __syncthreads();
    }
    int pe = ps[t] - (c0 + c1);
    excl[2 * t] = pe;
    excl[2 * t + 1] = pe + c0;
    __syncthreads();

    // row pointers for this bucket's 512 node slots + end sentinel
    int nb = b * RPS;
    rp[nb + 2 * t] = s0 + excl[2 * t];
    rp[nb + 2 * t + 1] = s0 + excl[2 * t + 1];
    if (t == 0) rp[nb + 512] = s0 + n;

    // LDS scatter (pairs re-read), then coalesced copy out
    for (int i = t; i < n; i += 256) {
        unsigned p = pairs[s0 + i];
        outl[excl[p >> 17] + rk[i]] = (int)(p & 0x1FFFFu);
    }
    __syncthreads();
    for (int i = t; i < n; i += 256)
        pool[s0 + i] = outl[i];
}

// ---------------- gather: one node per wave, 64 lanes x 2B fp8 -------------
// fp8 rows are 128B = 1 cache line per edge.  rp index: bucket-strided RPS.
// Drug nodes interleave dd/pd segments (4+4 loads in flight).
__device__ __forceinline__ int rpi(int node)
{
    return (node >> 9) * RPS + (node & 511);
}

__device__ __forceinline__ void accw(unsigned short w, f32x2* acc)
{
    float lo = __uint_as_float((unsigned)(w & 0xFFu) << 20);
    float hi = __uint_as_float((unsigned)(w >> 8) << 20);
    acc->x = fmaf(lo, 0x1p120f, acc->x);
    acc->y = fmaf(hi, 0x1p120f, acc->y);
}

__device__ __forceinline__ void acc_seg(
    const int* __restrict__ pool, int s, int e,
    const unsigned short* __restrict__ y, int lane, f32x2* acc)
{
    int j = s;
    for (; j + 8 <= e; j += 8) {
        unsigned short u[8];
#pragma unroll
        for (int t = 0; t < 8; t++)
            u[t] = y[(long)pool[j + t] * 64 + lane];
#pragma unroll
        for (int t = 0; t < 8; t++) accw(u[t], acc);
    }
    if (j + 4 <= e) {
        unsigned short u[4];
#pragma unroll
        for (int t = 0; t < 4; t++)
            u[t] = y[(long)pool[j + t] * 64 + lane];
#pragma unroll
        for (int t = 0; t < 4; t++) accw(u[t], acc);
        j += 4;
    }
    if (j + 2 <= e) {
        unsigned short u0 = y[(long)pool[j] * 64 + lane];
        unsigned short u1 = y[(long)pool[j + 1] * 64 + lane];
        accw(u0, acc); accw(u1, acc);
        j += 2;
    }
    if (j < e)
        accw(y[(long)pool[j] * 64 + lane], acc);
}

__global__ __launch_bounds__(256) void gather_kernel(
    const int* __restrict__ rp, const int* __restrict__ pool,
    const unsigned short* __restrict__ y_dd,
    const unsigned short* __restrict__ y_pd,
    const unsigned short* __restrict__ y_dp,
    bf16* __restrict__ agg_d, bf16* __restrict__ agg_p)
{
    int wid = blockIdx.x * 4 + (threadIdx.x >> 6);
    int lane = threadIdx.x & 63;

    if (wid < ND) {
        int g = wid;
        int i1r = rpi(g), i2r = rpi(ND + g);
        int s1 = rp[i1r], e1 = rp[i1r + 1];
        int s2 = rp[i2r], e2 = rp[i2r + 1];
        f32x2 a; a.x = 0.f; a.y = 0.f;
        f32x2 b; b.x = 0.f; b.y = 0.f;
        int j1 = s1, j2 = s2;
        // interleaved 4+4: both segments' loads in flight together
        while (j1 + 4 <= e1 && j2 + 4 <= e2) {
            unsigned short ua[4], ub[4];
#pragma unroll
            for (int t = 0; t < 4; t++)
                ua[t] = y_dd[(long)pool[j1 + t] * 64 + lane];
#pragma unroll
            for (int t = 0; t < 4; t++)
                ub[t] = y_pd[(long)pool[j2 + t] * 64 + lane];
#pragma unroll
            for (int t = 0; t < 4; t++) accw(ua[t], &a);
#pragma unroll
            for (int t = 0; t < 4; t++) accw(ub[t], &b);
            j1 += 4; j2 += 4;
        }
        acc_seg(pool, j1, e1, y_dd, lane, &a);
        acc_seg(pool, j2, e2, y_pd, lane, &b);
        float i1 = 0.5f / (float)max(e1 - s1, 1);
        float i2 = 0.5f / (float)max(e2 - s2, 1);
        f32x2 r = a * i1 + b * i2;
        bf16x2 o; o[0] = (bf16)r.x; o[1] = (bf16)r.y;
        *(bf16x2*)(agg_d + (long)g * D + lane * 2) = o;
    } else if (wid < ND + NP) {
        int p = wid - ND;
        int ir = rpi(2 * ND + p);
        int s1 = rp[ir], e1 = rp[ir + 1];
        f32x2 a; a.x = 0.f; a.y = 0.f;
        acc_seg(pool, s1, e1, y_dp, lane, &a);
        float i1 = 1.0f / (float)max(e1 - s1, 1);
        f32x2 r = a * i1;
        bf16x2 o; o[0] = (bf16)r.x; o[1] = (bf16)r.y;
        *(bf16x2*)(agg_p + (long)p * D + lane * 2) = o;
    }
}

// ---------------- fused node update: GEMM(K=256) + bias+relu+residual+LN ---
__device__ __forceinline__ void node_update_body(
    const float* __restrict__ x, const bf16* __restrict__ agg,
    const bf16* __restrict__ W, const float* __restrict__ b,
    const float* __restrict__ g, const float* __restrict__ be,
    float* __restrict__ out, int M, int blk)
{
    int lane = threadIdx.x & 63;
    int wave = threadIdx.x >> 6;
    int q = lane >> 4, c = lane & 15;
    int mb = blk * 256 + wave * 64;

    f32x4 acc[4][8];
#pragma unroll
    for (int mt = 0; mt < 4; mt++)
#pragma unroll
        for (int nt = 0; nt < 8; nt++) acc[mt][nt] = 0;

#pragma unroll
    for (int kb = 0; kb < 8; kb++) {
        bf16x8 a[4];
#pragma unroll
        for (int mt = 0; mt < 4; mt++) {
            int row = min(mb + mt * 16 + c, M - 1);
            if (kb < 4)
                a[mt] = load_a_f32(x + (long)row * D + kb * 32 + q * 8);
            else
                a[mt] = *(const bf16x8*)(agg + (long)row * D + (kb - 4) * 32 + q * 8);
        }
#pragma unroll
        for (int nt = 0; nt < 8; nt++) {
            bf16x8 bw = *(const bf16x8*)(W + (nt * 16 + c) * (2 * D) + kb * 32 + q * 8);
#pragma unroll
            for (int mt = 0; mt < 4; mt++)
                acc[mt][nt] = __builtin_amdgcn_mfma_f32_16x16x32_bf16(a[mt], bw, acc[mt][nt], 0, 0, 0);
        }
    }

    float bv[8], gv[8], bev[8];
#pragma unroll
    for (int nt = 0; nt < 8; nt++) {
        int col = nt * 16 + c;
        bv[nt] = b[col]; gv[nt] = g[col]; bev[nt] = be[col];
    }
#pragma unroll
    for (int mt = 0; mt < 4; mt++)
#pragma unroll
        for (int r = 0; r < 4; r++) {
            int row = mb + mt * 16 + q * 4 + r;
            int rowc = min(row, M - 1);
            const float* xr = x + (long)rowc * D + c;
            float v[8];
            float sum = 0.f, sq = 0.f;
#pragma unroll
            for (int nt = 0; nt < 8; nt++) {
                float h = fmaxf(acc[mt][nt][r] + bv[nt], 0.f);
                float t = h + xr[nt * 16];
                v[nt] = t; sum += t; sq += t * t;
            }
#pragma unroll
            for (int m = 1; m < 16; m <<= 1) {
                sum += __shfl_xor(sum, m, 64);
                sq  += __shfl_xor(sq,  m, 64);
            }
            float mu   = sum * (1.f / 128.f);
            float var  = sq  * (1.f / 128.f) - mu * mu;
            float rstd = rsqrtf(var + 1e-5f);
            if (row < M) {
                float* op = out + (long)row * D + c;
#pragma unroll
                for (int nt = 0; nt < 8; nt++)
                    op[nt * 16] = (v[nt] - mu) * rstd * gv[nt] + bev[nt];
            }
        }
}

__global__ __launch_bounds__(256, 2) void node_update_kernel(
    const float* __restrict__ x_drug, const float* __restrict__ x_prot,
    const bf16* __restrict__ agg_d, const bf16* __restrict__ agg_p,
    const bf16* __restrict__ Wdrug, const float* __restrict__ b_drug,
    const float* __restrict__ g_drug, const float* __restrict__ be_drug,
    const bf16* __restrict__ Wprot, const float* __restrict__ b_prot,
    const float* __restrict__ g_prot, const float* __restrict__ be_prot,
    float* __restrict__ out)
{
    int blk = blockIdx.x;
    if (blk < NU_BD)
        node_update_body(x_drug, agg_d, Wdrug, b_drug, g_drug, be_drug,
                         out, ND, blk);
    else
        node_update_body(x_prot, agg_p, Wprot, b_prot, g_prot, be_prot,
                         out + (long)ND * D, NP, blk - NU_BD);
}

extern "C" void kernel_launch(void* const* d_in, const int* in_sizes, int n_in,
                              void* d_out, int out_size, void* d_ws, size_t ws_size,
                              hipStream_t stream)
{
    const float* x_drug  = (const float*)d_in[0];
    const float* x_prot  = (const float*)d_in[1];
    const float* Wagg_dd = (const float*)d_in[2];
    const float* Wagg_dp = (const float*)d_in[3];
    const float* Wagg_pd = (const float*)d_in[4];
    const float* W_drug  = (const float*)d_in[5];
    const float* b_drug  = (const float*)d_in[6];
    const float* W_prot  = (const float*)d_in[7];
    const float* b_prot  = (const float*)d_in[8];
    const float* g_drug  = (const float*)d_in[9];
    const float* be_drug = (const float*)d_in[10];
    const float* g_prot  = (const float*)d_in[11];
    const float* be_prot = (const float*)d_in[12];
    const int* dd_src = (const int*)d_in[13];
    const int* dd_dst = (const int*)d_in[14];
    const int* dp_src = (const int*)d_in[15];
    const int* dp_dst = (const int*)d_in[16];
    const int* pd_src = (const int*)d_in[17];
    const int* pd_dst = (const int*)d_in[18];

    char* ws = (char*)d_ws;
    bf16* Wdd   = (bf16*)(ws + OFF_WDD);
    bf16* Wdp   = (bf16*)(ws + OFF_WDP);
    bf16* Wpd   = (bf16*)(ws + OFF_WPD);
    bf16* Wdrug = (bf16*)(ws + OFF_WDRUG);
    bf16* Wprot = (bf16*)(ws + OFF_WPROT);
    unsigned char* y_dd = (unsigned char*)(ws + OFF_YDD);
    unsigned char* y_dp = (unsigned char*)(ws + OFF_YDP);
    unsigned char* y_pd = (unsigned char*)(ws + OFF_YPD);
    bf16* agg_d = (bf16*)(ws + OFF_AGGD);
    bf16* agg_p = (bf16*)(ws + OFF_AGGP);
    int* gcur   = (int*)(ws + OFF_GCUR);
    int* rp     = (int*)(ws + OFF_RP);
    unsigned* pairs = (unsigned*)(ws + OFF_PAIRS);
    int* pool   = (int*)(ws + OFF_POOL);
    float* out  = (float*)d_out;

    // 1) weights->bf16 (+K-permutation for node-update W) + zero gcur
    prep_kernel<<<dim3(128, 6), 256, 0, stream>>>(
        Wagg_dd, Wagg_dp, Wagg_pd, W_drug, W_prot,
        Wdd, Wdp, Wpd, Wdrug, Wprot, gcur);

    // 2) single-pass binning into static bucket regions (no hist/scan)
    binA_kernel<<<NBLKA, 256, 0, stream>>>(
        dd_src, dd_dst, pd_src, pd_dst, dp_src, dp_dst, gcur, pairs);

    // 3) per-bucket counting sort -> pool + rp (513-stride with sentinel)
    sortB_kernel<<<NBC, 256, 0, stream>>>(gcur, pairs, pool, rp);

    // 4) per-node transforms (fp8 y) -- right before gather so y is hot
    transform_kernel<<<TF_BD + TF_BP, 256, 0, stream>>>(
        x_drug, x_prot, Wdd, Wdp, Wpd, y_dd, y_dp, y_pd);

    // 5) gather + per-relation mean (one node per wave, fp8 rows = 1 line)
    gather_kernel<<<(ND + NP + 3) / 4, 256, 0, stream>>>(
        rp, pool, (const unsigned short*)y_dd, (const unsigned short*)y_pd,
        (const unsigned short*)y_dp, agg_d, agg_p);

    // 6) fused node updates (drug rows then prot rows of out)
    node_update_kernel<<<NU_BD + NU_BP, 256, 0, stream>>>(
        x_drug, x_prot, agg_d, agg_p,
        Wdrug, b_drug, g_drug, be_drug,
        Wprot, b_prot, g_prot, be_prot, out);
}